// Round 10
// baseline (1829.787 us; speedup 1.0000x reference)
//
#include <hip/hip_runtime.h>
#include <math.h>

#define NS 1024
#define NA 2048
#define CIN 16
#define CC 32
#define LL 150
#define LC 75

typedef __attribute__((ext_vector_type(8))) short short8;
typedef __attribute__((ext_vector_type(4))) float float4v;

__device__ __forceinline__ unsigned short f2bf(float f) {
  // round-to-nearest-even fp32 -> bf16
  unsigned int u = __float_as_uint(f);
  unsigned int r = (u + 0x7FFFu + ((u >> 16) & 1u)) >> 16;
  return (unsigned short)r;
}

// ---------------------------------------------------------------------------
// K1 v6: conv1d(k=5,pad=2) + ReLU + sum over 16 reads — WAVE-PRIVATE, NO
// BARRIERS. Root cause of the 180-215us plateau (v1/v3/v5): the
// stage->barrier->MFMA->barrier chain puts full memory latency on the
// critical path every read (~32K cyc/iter measured vs ~5K of work).
// Fix: each of the 2 waves stages ALL 616 slots into its OWN LDS buffer and
// MFMAs only its own 80 output columns. Zero __syncthreads: within a wave,
// DS ops are in-order and compiler aliasing inserts the lgkmcnt waits; across
// waves nothing is shared. The compiler is now free to software-pipeline
// read r+1's global loads above read r's MFMA. Staging is duplicated 2x/block
// but a read is 9.6 KB -> L1-resident (no extra HBM traffic).
// LDS 2 x 9856 B; 8 blocks/CU (grid-limited); VGPR ~110 -> no clamp.
// ---------------------------------------------------------------------------
__global__ __launch_bounds__(128) void k_conv_sum_mfma(const float* __restrict__ x,
                                                       const float* __restrict__ w,
                                                       float* __restrict__ red) {
  __shared__ unsigned short xs[2][154 * 32];   // one 9856B buffer per wave
  const int a = blockIdx.x;
  const int tid = threadIdx.x;
  const int lane = tid & 63;
  const int wv = tid >> 6;                     // 0..1, owns cols [80wv, 80wv+80)
  unsigned short* __restrict__ myxs = xs[wv];

  // A-fragments (weights) -> registers. lane holds A[m=lane&15][k=8*(lane>>4)+j]
  short8 afr[2][3];
  {
    const int mrow = lane & 15;
    const int h = lane >> 4;
    for (int mt = 0; mt < 2; ++mt) {
      const int c = mt * 16 + mrow;
      for (int s = 0; s < 3; ++s) {
        short8 f;
#pragma unroll
        for (int j = 0; j < 8; ++j) {
          int ic = 4 * h + (j >> 1);
          int tap = 2 * s + (j & 1);
          float wval = (tap < 5) ? w[c * 80 + ic * 5 + tap] : 0.f;
          f[j] = (short)f2bf(wval);
        }
        afr[mt][s] = f;
      }
    }
  }

  float4v sum[2][5];
#pragma unroll
  for (int mt = 0; mt < 2; ++mt)
#pragma unroll
    for (int nt = 0; nt < 5; ++nt) sum[mt][nt] = (float4v)(0.f);

  const int nbase = wv * 80;
  const int nrow = lane & 15;
  const int hh = lane >> 4;
  const float4v zf = (float4v)(0.f);

  for (int r = 0; r < 16; ++r) {
    // ---- wave-private staging: this wave writes ALL 616 slots of its buffer
    const float* xr = x + (size_t)(a * 16 + r) * (CIN * LL);
    for (int s = lane; s < 616; s += 64) {
      const int p = s >> 2;
      const int h4 = (s & 3) * 4;                  // ic base for this slot
      const float* xb = xr + h4 * LL + p;
      const bool qe_ok = (p >= 2) && (p <= 151);   // px[p]   = x[p-2]
      const bool qo_ok = (p >= 1) && (p <= 150);   // px[p+1] = x[p-1]
      short8 f;
#pragma unroll
      for (int c = 0; c < 4; ++c) {
        float ve = qe_ok ? xb[c * LL - 2] : 0.f;
        float vo = qo_ok ? xb[c * LL - 1] : 0.f;
        f[2 * c]     = (short)f2bf(ve);
        f[2 * c + 1] = (short)f2bf(vo);
      }
      *(short8*)&myxs[s * 8] = f;                  // conflict-free b128 write
    }
    // no barrier: same-wave ds_write -> ds_read is ordered by lgkmcnt (DS
    // in-order per wave); other wave never touches this buffer.

    float4v acc[2][5];
#pragma unroll
    for (int s = 0; s < 3; ++s) {
#pragma unroll
      for (int nt = 0; nt < 5; ++nt) {
        int p = nbase + nt * 16 + nrow + 2 * s;
        if (p >= 154) p -= 154;                    // only for discarded cols
        short8 bfrag = *(const short8*)&myxs[(4 * p + hh) * 8];
#pragma unroll
        for (int mt = 0; mt < 2; ++mt) {
          acc[mt][nt] = __builtin_amdgcn_mfma_f32_16x16x32_bf16(
              afr[mt][s], bfrag, (s == 0) ? zf : acc[mt][nt], 0, 0, 0);
        }
      }
    }
#pragma unroll
    for (int mt = 0; mt < 2; ++mt)
#pragma unroll
      for (int nt = 0; nt < 5; ++nt)
#pragma unroll
        for (int q = 0; q < 4; ++q) sum[mt][nt][q] += fmaxf(acc[mt][nt][q], 0.f);
  }

  // C/D layout (16x16): col = lane&15 -> l, row = (lane>>4)*4+reg -> c
  const int ccol = lane & 15;
  const int crow4 = (lane >> 4) * 4;
  for (int mt = 0; mt < 2; ++mt)
    for (int nt = 0; nt < 5; ++nt) {
      int l = nbase + nt * 16 + ccol;
      if (l < LL) {
#pragma unroll
        for (int q = 0; q < 4; ++q) {
          int c = mt * 16 + crow4 + q;
          red[(size_t)a * (CC * LL) + c * LL + l] = sum[mt][nt][q];
        }
      }
    }
}

// ---------------------------------------------------------------------------
// K2: red2 = relu(comb_w @ [red0|red1]) in place over red0 (unchanged)
// ---------------------------------------------------------------------------
__global__ __launch_bounds__(256) void k_comb(const float* __restrict__ red0,
                                              const float* __restrict__ red1,
                                              const float* __restrict__ cw,
                                              float* __restrict__ out) {
  __shared__ float ins[64][152];
  __shared__ float cwl[64][CC];
  const int a = blockIdx.x;
  const int tid = threadIdx.x;

  for (int i = tid; i < 64 * CC; i += 256) {
    int c = i & 31; int c2 = i >> 5;
    cwl[c2][c] = cw[c * 64 + c2];
  }
  for (int i = tid; i < CC * LL; i += 256) {
    int c2 = i / LL; int l = i - c2 * LL;
    ins[c2][l] = red0[(size_t)a * (CC * LL) + i];
    ins[32 + c2][l] = red1[(size_t)a * (CC * LL) + i];
  }
  __syncthreads();

  const int c = tid & 31;
  const int lg = tid >> 5;
  const int l0 = lg * 19;
  const int nl = (LL - l0 < 19) ? (LL - l0) : 19;
  float v[19];
#pragma unroll
  for (int j = 0; j < 19; ++j) v[j] = 0.f;
  for (int c2 = 0; c2 < 64; ++c2) {
    float wv = cwl[c2][c];
#pragma unroll
    for (int j = 0; j < 19; ++j) v[j] += wv * ins[c2][l0 + j];
  }
  float* o = out + (size_t)a * (CC * LL) + c * LL + l0;
  for (int j = 0; j < nl; ++j) o[j] = fmaxf(v[j], 0.f);
}

// ---------------------------------------------------------------------------
// K3 v2: per-SITE fused compressor (unchanged from round 7).
// cfa0 = relu(v0), cfa1 = relu(v1), cfs = relu(v0+v1) in one pass.
// ---------------------------------------------------------------------------
__global__ __launch_bounds__(256) void k_compress2(const float* __restrict__ src,
                                                   const float* __restrict__ w,
                                                   float* __restrict__ cfa,
                                                   float* __restrict__ cfs) {
  __shared__ float ins0[CC][164];
  __shared__ float ins1[CC][164];
  __shared__ float ws[CC][3][CC];
  const int sfull = blockIdx.x;
  const int tid = threadIdx.x;

  for (int i = tid; i < CC * 3 * CC; i += 256) {
    int c = i & 31; int kk = i >> 5; int ic = kk / 3; int t = kk - ic * 3;
    ws[ic][t][c] = w[c * (CC * 3) + ic * 3 + t];
  }
  if (tid < CC) {
    ins0[tid][0] = 0.f; ins0[tid][1] = 0.f; ins0[tid][152] = 0.f; ins0[tid][153] = 0.f;
    ins1[tid][0] = 0.f; ins1[tid][1] = 0.f; ins1[tid][152] = 0.f; ins1[tid][153] = 0.f;
  }
  {
    const float* s0 = src + (size_t)(2 * sfull) * (CC * LL);
    const float* s1 = s0 + CC * LL;
    for (int i = tid; i < CC * LL; i += 256) {
      int ic = i / LL; int l = i - ic * LL;
      ins0[ic][l + 2] = s0[i];
      ins1[ic][l + 2] = s1[i];
    }
  }
  __syncthreads();

  const int c = tid & 31;
  const int jg = tid >> 5;
  const int j0 = jg * 10;
  const int nj = (LC - j0 < 10) ? (LC - j0) : 10;
  float v0[10], v1[10];
#pragma unroll
  for (int j = 0; j < 10; ++j) { v0[j] = 0.f; v1[j] = 0.f; }
  for (int ic = 0; ic < CC; ++ic) {
    float w0 = ws[ic][0][c], w1 = ws[ic][1][c], w2 = ws[ic][2][c];
    float xa[12], xb[12];
#pragma unroll
    for (int i = 0; i < 12; ++i) {
      xa[i] = ins0[ic][2 * j0 + 2 * i];
      xb[i] = ins1[ic][2 * j0 + 2 * i];
    }
#pragma unroll
    for (int j = 0; j < 10; ++j) {
      v0[j] += w0 * xa[j] + w1 * xa[j + 1] + w2 * xa[j + 2];
      v1[j] += w0 * xb[j] + w1 * xb[j + 1] + w2 * xb[j + 2];
    }
  }
  float* oa0 = cfa + (size_t)(2 * sfull) * (CC * LC) + c * LC + j0;
  float* oa1 = oa0 + CC * LC;
  float* os  = cfs + (size_t)sfull * (CC * LC) + c * LC + j0;
  for (int j = 0; j < nj; ++j) {
    float a0 = v0[j], a1 = v1[j];
    oa0[j] = fmaxf(a0, 0.f);
    oa1[j] = fmaxf(a1, 0.f);
    os[j]  = fmaxf(a0 + a1, 0.f);
  }
}

// ---------------------------------------------------------------------------
// K4 v5: per-ALLELE fused cross-attention, spill-free (unchanged from round 5)
// ---------------------------------------------------------------------------
#define BKV   0
#define BW    4800
#define BQT   8064
#define BCF   10464
#define BKB   10464
#define BVB   15328
#define BROWP 0
#define BPART 6080
#define BMS   6336
#define ARENA 20320

__global__ __launch_bounds__(256) void k_attn(const float* __restrict__ cfa,
                                              const float* __restrict__ cfs0,
                                              const float* __restrict__ wq,
                                              const float* __restrict__ wk,
                                              const float* __restrict__ wv,
                                              const float* __restrict__ wo,
                                              float* __restrict__ eout) {
  __shared__ float ar[ARENA];
  const int a = blockIdx.x;
  const int s = a >> 1;
  const int tid = threadIdx.x;
  const int g = tid >> 5;
  const int t = tid & 31;

  // ---- phase A: stage weights (in-major, stride 33), kv, cf ----
  for (int i = tid; i < CC * CC; i += 256) {
    int o = i >> 5, ii = i & 31;
    ar[BW + ii * 33 + o]        = wq[i];
    ar[BW + 1056 + ii * 33 + o] = wk[i];
    ar[BW + 2112 + ii * 33 + o] = wv[i];
  }
  {
    const float* sg = cfs0 + (size_t)s * (CC * LC);
    const float* a0 = cfa + (size_t)(2 * s) * (CC * LC);
    const float* a1 = a0 + CC * LC;
    const int sel = a & 1;
    for (int i = tid; i < CC * LC; i += 256) {
      int c = i / 75, l = i - c * 75;
      float v0 = a0[i], v1 = a1[i];
      ar[BKV + c * 150 + l]      = sg[i];
      ar[BKV + c * 150 + 75 + l] = v0 + v1;
      ar[BCF + c * 77 + l]       = sel ? v1 : v0;
    }
  }
  __syncthreads();

  // ---- phase B1: q -> QT (LDS), cf partial column-sum ----
  float cfp = 0.f;
  {
    float wqc[32];
#pragma unroll
    for (int ii = 0; ii < 32; ++ii) wqc[ii] = ar[BW + ii * 33 + t];
    for (int row = g; row < 75; row += 8) {
      float acc = 0.f;
#pragma unroll
      for (int ii = 0; ii < 32; ++ii) acc += wqc[ii] * ar[BCF + ii * 77 + row];
      ar[BQT + row * 32 + t] = acc;
      cfp += ar[BCF + t * 77 + row];
    }
  }
  __syncthreads();   // QT visible; CF reads done -> KB may overwrite

  // ---- phase B2: k,v projection -> KB (over CF), VB ----
  {
    float wkc[32], wvc[32];
#pragma unroll
    for (int ii = 0; ii < 32; ++ii) {
      wkc[ii] = ar[BW + 1056 + ii * 33 + t];
      wvc[ii] = ar[BW + 2112 + ii * 33 + t];
    }
    for (int idx = tid; idx < CC * LL; idx += 256) {
      int o = idx & 31, m = idx >> 5;
      float ka = 0.f, va = 0.f;
#pragma unroll
      for (int ii = 0; ii < 32; ++ii) {
        float x = ar[BKV + ii * 150 + m];
        ka += wkc[ii] * x;
        va += wvc[ii] * x;
      }
      ar[BKB + o * 152 + m] = ka;
      ar[BVB + o * 156 + m] = va;
    }
    if (tid < 64) ar[BVB + (tid >> 1) * 156 + 150 + (tid & 1)] = 0.f;  // PV pad
  }
  __syncthreads();   // KB/VB ready; KV+W dead -> ROWP may overwrite

  // ---- phase D: per-chunk (5 rows) scores -> softmax -> PV ----
  float ms = 0.f;
  const int rbase = BROWP + g * 760;
  const float scale = 0.17677669529663687f;   // 1/sqrt(32)
#pragma unroll 1
  for (int cc = 0; cc < 2; ++cc) {
    const int ch = g + 8 * cc;
    if (ch >= 15) break;
    const int r0 = ch * 5;

    float2 acc[5][3];
#pragma unroll
    for (int i = 0; i < 5; ++i)
#pragma unroll
      for (int u = 0; u < 3; ++u) acc[i][u] = make_float2(0.f, 0.f);

#pragma unroll 1
    for (int c2 = 0; c2 < 32; c2 += 2) {
      float2 q01[5];
#pragma unroll
      for (int i = 0; i < 5; ++i) q01[i] = *(const float2*)&ar[BQT + (r0 + i) * 32 + c2];
      const int cb0 = BKB + c2 * 152 + 2 * t;
      const int cb1 = cb0 + 152;
      float2 ka0 = *(const float2*)&ar[cb0];
      float2 ka1 = *(const float2*)&ar[cb0 + 64];
      float2 ka2 = *(const float2*)&ar[cb0 + 128];
      float2 kb0 = *(const float2*)&ar[cb1];
      float2 kb1 = *(const float2*)&ar[cb1 + 64];
      float2 kb2 = *(const float2*)&ar[cb1 + 128];
#pragma unroll
      for (int i = 0; i < 5; ++i) {
        acc[i][0].x += q01[i].x * ka0.x + q01[i].y * kb0.x;
        acc[i][0].y += q01[i].x * ka0.y + q01[i].y * kb0.y;
        acc[i][1].x += q01[i].x * ka1.x + q01[i].y * kb1.x;
        acc[i][1].y += q01[i].x * ka1.y + q01[i].y * kb1.y;
        acc[i][2].x += q01[i].x * ka2.x + q01[i].y * kb2.x;
        acc[i][2].y += q01[i].x * ka2.y + q01[i].y * kb2.y;
      }
    }

    float inv[5];
#pragma unroll
    for (int i = 0; i < 5; ++i) {
      float s0x = acc[i][0].x * scale, s0y = acc[i][0].y * scale;
      float s1x = acc[i][1].x * scale, s1y = acc[i][1].y * scale;
      float s2x = acc[i][2].x * scale, s2y = acc[i][2].y * scale;
      if (t >= 11) { s2x = -1e30f; s2y = -1e30f; }   // m=128+2t >= 150
      float mx = fmaxf(fmaxf(fmaxf(s0x, s0y), fmaxf(s1x, s1y)), fmaxf(s2x, s2y));
#pragma unroll
      for (int off = 16; off > 0; off >>= 1) mx = fmaxf(mx, __shfl_xor(mx, off, 32));
      float p0x = __expf(s0x - mx), p0y = __expf(s0y - mx);
      float p1x = __expf(s1x - mx), p1y = __expf(s1y - mx);
      float p2x = __expf(s2x - mx), p2y = __expf(s2y - mx);
      float ss = p0x + p0y + p1x + p1y + p2x + p2y;
#pragma unroll
      for (int off = 16; off > 0; off >>= 1) ss += __shfl_xor(ss, off, 32);
      inv[i] = 1.f / ss;
      const int rb = rbase + i * 152 + 2 * t;
      *(float2*)&ar[rb]      = make_float2(p0x, p0y);
      *(float2*)&ar[rb + 64] = make_float2(p1x, p1y);
      if (t <= 11) *(float2*)&ar[rb + 128] = make_float2(p2x, p2y);
    }

    float pv[5] = {0.f, 0.f, 0.f, 0.f, 0.f};
    for (int mq = 0; mq < 38; ++mq) {
      float4 vv = *(const float4*)&ar[BVB + t * 156 + 4 * mq];
#pragma unroll
      for (int i = 0; i < 5; ++i) {
        float4 pp = *(const float4*)&ar[rbase + i * 152 + 4 * mq];
        pv[i] += pp.x * vv.x + pp.y * vv.y + pp.z * vv.z + pp.w * vv.w;
      }
    }
#pragma unroll
    for (int i = 0; i < 5; ++i) ms += pv[i] * inv[i];
  }

  ar[BPART + g * 32 + t] = cfp + ms;
  __syncthreads();

  // ---- epilogue: mean over l, project with wo ----
  if (tid < 32) {
    float tot = 0.f;
#pragma unroll
    for (int gg = 0; gg < 8; ++gg) tot += ar[BPART + gg * 32 + tid];
    ar[BMS + tid] = tot * (1.f / 75.f);
  }
  __syncthreads();
  if (tid < 2) {
    float e = 0.f;
#pragma unroll
    for (int c2 = 0; c2 < CC; ++c2) e += wo[tid * CC + c2] * ar[BMS + c2];
    eout[a * 2 + tid] = e;
  }
}

// ---------------------------------------------------------------------------
// K5: meta head per site (unchanged)
// ---------------------------------------------------------------------------
__global__ __launch_bounds__(64) void k_meta(const float* __restrict__ cfs0,
                                             const float* __restrict__ cfa2,
                                             const float* __restrict__ mw,
                                             const float* __restrict__ mb,
                                             float* __restrict__ mout) {
  __shared__ float feat[64];
  __shared__ float lgt[3];
  const int s = blockIdx.x;
  const int tid = threadIdx.x;
  float f = 0.f;
  if (tid < 32) {
    const float* p = cfs0 + (size_t)s * (CC * LC) + tid * LC;
    for (int l = 0; l < LC; ++l) f += p[l];
  } else {
    const float* p0 = cfa2 + (size_t)(2 * s) * (CC * LC) + (tid - 32) * LC;
    const float* p1 = cfa2 + (size_t)(2 * s + 1) * (CC * LC) + (tid - 32) * LC;
    for (int l = 0; l < LC; ++l) f += p0[l] + p1[l];
  }
  feat[tid] = f * (1.f / 75.f);
  __syncthreads();
  if (tid < 3) {
    float acc2 = mb[tid];
    for (int c2 = 0; c2 < 64; ++c2) acc2 += mw[tid * 64 + c2] * feat[c2];
    lgt[tid] = acc2;
  }
  __syncthreads();
  if (tid < 3) {
    float mx = fmaxf(lgt[0], fmaxf(lgt[1], lgt[2]));
    float e0 = __expf(lgt[0] - mx), e1 = __expf(lgt[1] - mx), e2 = __expf(lgt[2] - mx);
    mout[s * 3 + tid] = __expf(lgt[tid] - mx) / (e0 + e1 + e2);
  }
}

// ---------------------------------------------------------------------------
extern "C" void kernel_launch(void* const* d_in, const int* in_sizes, int n_in,
                              void* d_out, int out_size, void* d_ws, size_t ws_size,
                              hipStream_t stream) {
  const float* t0      = (const float*)d_in[0];
  const float* t1      = (const float*)d_in[1];
  const float* conv0_w = (const float*)d_in[2];
  const float* conv1_w = (const float*)d_in[3];
  const float* comp0_w = (const float*)d_in[4];
  const float* comp1_w = (const float*)d_in[5];
  const float* comp2_w = (const float*)d_in[6];
  const float* xq0 = (const float*)d_in[7];
  const float* xk0 = (const float*)d_in[8];
  const float* xv0 = (const float*)d_in[9];
  const float* xo0 = (const float*)d_in[10];
  const float* xq1 = (const float*)d_in[11];
  const float* xk1 = (const float*)d_in[12];
  const float* xv1 = (const float*)d_in[13];
  const float* xo1 = (const float*)d_in[14];
  const float* xq2 = (const float*)d_in[15];
  const float* xk2 = (const float*)d_in[16];
  const float* xv2 = (const float*)d_in[17];
  const float* xo2 = (const float*)d_in[18];
  const float* comb_w = (const float*)d_in[19];
  const float* meta_w = (const float*)d_in[20];
  const float* meta_b = (const float*)d_in[21];

  float* wsf  = (float*)d_ws;
  float* red0 = wsf;
  float* red1 = red0 + (size_t)NA * CC * LL;
  float* cfa  = red1 + (size_t)NA * CC * LL;
  float* cfs0 = cfa + (size_t)NA * CC * LC;
  float* out  = (float*)d_out;

  k_conv_sum_mfma<<<NA, 128, 0, stream>>>(t0, conv0_w, red0);
  k_conv_sum_mfma<<<NA, 128, 0, stream>>>(t1, conv1_w, red1);

  k_compress2<<<NS, 256, 0, stream>>>(red0, comp0_w, cfa, cfs0);
  k_attn<<<NA, 256, 0, stream>>>(cfa, cfs0, xq0, xk0, xv0, xo0, out + 0);

  k_compress2<<<NS, 256, 0, stream>>>(red1, comp1_w, cfa, cfs0);
  k_attn<<<NA, 256, 0, stream>>>(cfa, cfs0, xq1, xk1, xv1, xo1, out + 2 * NA);

  k_comb<<<NA, 256, 0, stream>>>(red0, red1, comb_w, red0);
  k_compress2<<<NS, 256, 0, stream>>>(red0, comp2_w, cfa, cfs0);
  k_attn<<<NA, 256, 0, stream>>>(cfa, cfs0, xq2, xk2, xv2, xo2, out + 4 * NA);

  k_meta<<<NS, 64, 0, stream>>>(cfs0, cfa, meta_w, meta_b, out + 6 * NA);
}

// Round 11
// 1479.510 us; speedup vs baseline: 1.2368x; 1.2368x over previous
//
#include <hip/hip_runtime.h>
#include <math.h>

#define NS 1024
#define NA 2048
#define CIN 16
#define CC 32
#define LL 150
#define LC 75

typedef __attribute__((ext_vector_type(8))) short short8;
typedef __attribute__((ext_vector_type(4))) float float4v;

__device__ __forceinline__ unsigned short f2bf(float f) {
  // round-to-nearest-even fp32 -> bf16
  unsigned int u = __float_as_uint(f);
  unsigned int r = (u + 0x7FFFu + ((u >> 16) & 1u)) >> 16;
  return (unsigned short)r;
}

__device__ __forceinline__ unsigned int pkbf(float lo, float hi) {
  return (unsigned int)f2bf(lo) | ((unsigned int)f2bf(hi) << 16);
}

// ---------------------------------------------------------------------------
// K1 v7: conv1d(k=5,pad=2) + ReLU + sum over 16 reads, bf16 MFMA implicit GEMM.
// Staging rewritten for LINE-EFFICIENT loads. Diagnosis (R9/R10): conv is
// memory-pipe-occupancy bound — old staging issued 8 scalar dword loads per
// slot at 600B stride (16 lines/instr, 25% line use); time scaled linearly
// with load-instr count (R10: 2x loads -> 1.57x time) while all pipes <25%.
// Key identity: adjacent u16 pairs of the slot layout are
// (x[ic][l], x[ic][l+1]) — consecutive input elements. So each (ic, 4-elem
// segment) thread does 2 aligned float2 loads + 1 scalar (64B fully used per
// row per instr) and writes 4 packed u32s at stride 64B (4-way bank alias =
// 1.58x, fine). u32 index for pack(px[p],px[p+1]) of channel ic:
//   16*p + 4*(ic>>2) + (ic&3),  value = bf(x[p-2]) | bf(x[p-1])<<16
// Boundary packs p=0,1 and right-pad p=150..153 handled explicitly.
// LDS image byte-identical to v1-v5; MFMA side untouched.
// v3 double-buffer / 1-barrier skeleton kept. 256 threads, 2x9856B LDS.
// ---------------------------------------------------------------------------
__global__ __launch_bounds__(256) void k_conv_sum_mfma(const float* __restrict__ x,
                                                       const float* __restrict__ w,
                                                       float* __restrict__ red) {
  __shared__ unsigned short xs[2][154 * 32];   // 2 x 616 slots of 16B
  const int a = blockIdx.x;
  const int tid = threadIdx.x;
  const int lane = tid & 63;
  const int wv = tid >> 6;

  // A-fragments (weights) -> registers. lane holds A[m=lane&15][k=8*(lane>>4)+j]
  short8 afr[2][3];
  {
    const int mrow = lane & 15;
    const int h = lane >> 4;
    for (int mt = 0; mt < 2; ++mt) {
      const int c = mt * 16 + mrow;
      for (int s = 0; s < 3; ++s) {
        short8 f;
#pragma unroll
        for (int j = 0; j < 8; ++j) {
          int ic = 4 * h + (j >> 1);
          int tap = 2 * s + (j & 1);
          float wval = (tap < 5) ? w[c * 80 + ic * 5 + tap] : 0.f;
          f[j] = (short)f2bf(wval);
        }
        afr[mt][s] = f;
      }
    }
  }

  float4v sum[2][3];
#pragma unroll
  for (int mt = 0; mt < 2; ++mt)
#pragma unroll
    for (int nt = 0; nt < 3; ++nt) sum[mt][nt] = (float4v)(0.f);

  const int nbase = wv * 48;
  const int nrow = lane & 15;
  const int hh = lane >> 4;
  const float4v zf = (float4v)(0.f);

  // stage read r into buffer buf — full LDS image (all p=0..153, all ics)
  auto stage = [&](int r, int buf) {
    const float* xr = x + (size_t)(a * 16 + r) * (CIN * LL);
    unsigned int* xb32 = (unsigned int*)xs[buf];
    // main packs: idx -> (ic = idx&15, seg = idx>>4), seg = 0..37
    for (int idx = tid; idx < 16 * 38; idx += 256) {
      const int ic = idx & 15;
      const int seg = idx >> 4;
      const int l0 = seg * 4;
      const float* row = xr + ic * LL;
      float v0, v1, v2, v3, v4;
      if (seg < 37) {
        float2 u = *(const float2*)(row + l0);       // 8B-aligned (row stride 600)
        float2 u2 = *(const float2*)(row + l0 + 2);
        v0 = u.x; v1 = u.y; v2 = u2.x; v3 = u2.y;
        v4 = row[l0 + 4];                            // l0+4 <= 148 < 150 always
      } else {                                       // seg 37: elements 148,149
        float2 u = *(const float2*)(row + 148);
        v0 = u.x; v1 = u.y; v2 = 0.f; v3 = 0.f; v4 = 0.f;
      }
      const int hb = 4 * (ic >> 2) + (ic & 3);
      unsigned int* b32 = xb32 + 16 * (l0 + 2) + hb;
      b32[0]  = pkbf(v0, v1);    // p = l0+2
      b32[16] = pkbf(v1, v2);    // p = l0+3
      b32[32] = pkbf(v2, v3);    // p = l0+4
      b32[48] = pkbf(v3, v4);    // p = l0+5   (seg37 -> p=153: zeros)
    }
    // boundary packs: p=0 -> (0,0); p=1 -> (0, x[ic][0])
    if (tid < 32) {
      const int ic = tid & 15;
      const int which = tid >> 4;
      const int hb = 4 * (ic >> 2) + (ic & 3);
      xb32[16 * which + hb] = which ? pkbf(0.f, xr[ic * LL]) : 0u;
    }
  };

  stage(0, 0);
  __syncthreads();

  for (int r = 0; r < 16; ++r) {
    const int cur = r & 1;
    if (r + 1 < 16) stage(r + 1, cur ^ 1);   // buf cur^1 last read pre-barrier — safe

    float4v acc[2][3];
#pragma unroll
    for (int s = 0; s < 3; ++s) {
#pragma unroll
      for (int nt = 0; nt < 3; ++nt) {
        int p = nbase + nt * 16 + nrow + 2 * s;
        if (p >= 154) p -= 154;                    // only for discarded cols
        short8 bfrag = *(const short8*)&xs[cur][(4 * p + hh) * 8];
#pragma unroll
        for (int mt = 0; mt < 2; ++mt) {
          acc[mt][nt] = __builtin_amdgcn_mfma_f32_16x16x32_bf16(
              afr[mt][s], bfrag, (s == 0) ? zf : acc[mt][nt], 0, 0, 0);
        }
      }
    }
#pragma unroll
    for (int mt = 0; mt < 2; ++mt)
#pragma unroll
      for (int nt = 0; nt < 3; ++nt)
#pragma unroll
        for (int q = 0; q < 4; ++q) sum[mt][nt][q] += fmaxf(acc[mt][nt][q], 0.f);

    __syncthreads();   // staging of r+1 done AND MFMA reads of r done
  }

  // C/D layout (16x16): col = lane&15 -> l, row = (lane>>4)*4+reg -> c
  const int ccol = lane & 15;
  const int crow4 = (lane >> 4) * 4;
  for (int mt = 0; mt < 2; ++mt)
    for (int nt = 0; nt < 3; ++nt) {
      int l = nbase + nt * 16 + ccol;
      if (l < LL) {
#pragma unroll
        for (int q = 0; q < 4; ++q) {
          int c = mt * 16 + crow4 + q;
          red[(size_t)a * (CC * LL) + c * LL + l] = sum[mt][nt][q];
        }
      }
    }
}

// ---------------------------------------------------------------------------
// K2: red2 = relu(comb_w @ [red0|red1]) in place over red0 (unchanged)
// ---------------------------------------------------------------------------
__global__ __launch_bounds__(256) void k_comb(const float* __restrict__ red0,
                                              const float* __restrict__ red1,
                                              const float* __restrict__ cw,
                                              float* __restrict__ out) {
  __shared__ float ins[64][152];
  __shared__ float cwl[64][CC];
  const int a = blockIdx.x;
  const int tid = threadIdx.x;

  for (int i = tid; i < 64 * CC; i += 256) {
    int c = i & 31; int c2 = i >> 5;
    cwl[c2][c] = cw[c * 64 + c2];
  }
  for (int i = tid; i < CC * LL; i += 256) {
    int c2 = i / LL; int l = i - c2 * LL;
    ins[c2][l] = red0[(size_t)a * (CC * LL) + i];
    ins[32 + c2][l] = red1[(size_t)a * (CC * LL) + i];
  }
  __syncthreads();

  const int c = tid & 31;
  const int lg = tid >> 5;
  const int l0 = lg * 19;
  const int nl = (LL - l0 < 19) ? (LL - l0) : 19;
  float v[19];
#pragma unroll
  for (int j = 0; j < 19; ++j) v[j] = 0.f;
  for (int c2 = 0; c2 < 64; ++c2) {
    float wv = cwl[c2][c];
#pragma unroll
    for (int j = 0; j < 19; ++j) v[j] += wv * ins[c2][l0 + j];
  }
  float* o = out + (size_t)a * (CC * LL) + c * LL + l0;
  for (int j = 0; j < nl; ++j) o[j] = fmaxf(v[j], 0.f);
}

// ---------------------------------------------------------------------------
// K3 v2: per-SITE fused compressor (unchanged from round 7).
// cfa0 = relu(v0), cfa1 = relu(v1), cfs = relu(v0+v1) in one pass.
// ---------------------------------------------------------------------------
__global__ __launch_bounds__(256) void k_compress2(const float* __restrict__ src,
                                                   const float* __restrict__ w,
                                                   float* __restrict__ cfa,
                                                   float* __restrict__ cfs) {
  __shared__ float ins0[CC][164];
  __shared__ float ins1[CC][164];
  __shared__ float ws[CC][3][CC];
  const int sfull = blockIdx.x;
  const int tid = threadIdx.x;

  for (int i = tid; i < CC * 3 * CC; i += 256) {
    int c = i & 31; int kk = i >> 5; int ic = kk / 3; int t = kk - ic * 3;
    ws[ic][t][c] = w[c * (CC * 3) + ic * 3 + t];
  }
  if (tid < CC) {
    ins0[tid][0] = 0.f; ins0[tid][1] = 0.f; ins0[tid][152] = 0.f; ins0[tid][153] = 0.f;
    ins1[tid][0] = 0.f; ins1[tid][1] = 0.f; ins1[tid][152] = 0.f; ins1[tid][153] = 0.f;
  }
  {
    const float* s0 = src + (size_t)(2 * sfull) * (CC * LL);
    const float* s1 = s0 + CC * LL;
    for (int i = tid; i < CC * LL; i += 256) {
      int ic = i / LL; int l = i - ic * LL;
      ins0[ic][l + 2] = s0[i];
      ins1[ic][l + 2] = s1[i];
    }
  }
  __syncthreads();

  const int c = tid & 31;
  const int jg = tid >> 5;
  const int j0 = jg * 10;
  const int nj = (LC - j0 < 10) ? (LC - j0) : 10;
  float v0[10], v1[10];
#pragma unroll
  for (int j = 0; j < 10; ++j) { v0[j] = 0.f; v1[j] = 0.f; }
  for (int ic = 0; ic < CC; ++ic) {
    float w0 = ws[ic][0][c], w1 = ws[ic][1][c], w2 = ws[ic][2][c];
    float xa[12], xb[12];
#pragma unroll
    for (int i = 0; i < 12; ++i) {
      xa[i] = ins0[ic][2 * j0 + 2 * i];
      xb[i] = ins1[ic][2 * j0 + 2 * i];
    }
#pragma unroll
    for (int j = 0; j < 10; ++j) {
      v0[j] += w0 * xa[j] + w1 * xa[j + 1] + w2 * xa[j + 2];
      v1[j] += w0 * xb[j] + w1 * xb[j + 1] + w2 * xb[j + 2];
    }
  }
  float* oa0 = cfa + (size_t)(2 * sfull) * (CC * LC) + c * LC + j0;
  float* oa1 = oa0 + CC * LC;
  float* os  = cfs + (size_t)sfull * (CC * LC) + c * LC + j0;
  for (int j = 0; j < nj; ++j) {
    float a0 = v0[j], a1 = v1[j];
    oa0[j] = fmaxf(a0, 0.f);
    oa1[j] = fmaxf(a1, 0.f);
    os[j]  = fmaxf(a0 + a1, 0.f);
  }
}

// ---------------------------------------------------------------------------
// K4 v5: per-ALLELE fused cross-attention, spill-free (unchanged from round 5)
// ---------------------------------------------------------------------------
#define BKV   0
#define BW    4800
#define BQT   8064
#define BCF   10464
#define BKB   10464
#define BVB   15328
#define BROWP 0
#define BPART 6080
#define BMS   6336
#define ARENA 20320

__global__ __launch_bounds__(256) void k_attn(const float* __restrict__ cfa,
                                              const float* __restrict__ cfs0,
                                              const float* __restrict__ wq,
                                              const float* __restrict__ wk,
                                              const float* __restrict__ wv,
                                              const float* __restrict__ wo,
                                              float* __restrict__ eout) {
  __shared__ float ar[ARENA];
  const int a = blockIdx.x;
  const int s = a >> 1;
  const int tid = threadIdx.x;
  const int g = tid >> 5;
  const int t = tid & 31;

  // ---- phase A: stage weights (in-major, stride 33), kv, cf ----
  for (int i = tid; i < CC * CC; i += 256) {
    int o = i >> 5, ii = i & 31;
    ar[BW + ii * 33 + o]        = wq[i];
    ar[BW + 1056 + ii * 33 + o] = wk[i];
    ar[BW + 2112 + ii * 33 + o] = wv[i];
  }
  {
    const float* sg = cfs0 + (size_t)s * (CC * LC);
    const float* a0 = cfa + (size_t)(2 * s) * (CC * LC);
    const float* a1 = a0 + CC * LC;
    const int sel = a & 1;
    for (int i = tid; i < CC * LC; i += 256) {
      int c = i / 75, l = i - c * 75;
      float v0 = a0[i], v1 = a1[i];
      ar[BKV + c * 150 + l]      = sg[i];
      ar[BKV + c * 150 + 75 + l] = v0 + v1;
      ar[BCF + c * 77 + l]       = sel ? v1 : v0;
    }
  }
  __syncthreads();

  // ---- phase B1: q -> QT (LDS), cf partial column-sum ----
  float cfp = 0.f;
  {
    float wqc[32];
#pragma unroll
    for (int ii = 0; ii < 32; ++ii) wqc[ii] = ar[BW + ii * 33 + t];
    for (int row = g; row < 75; row += 8) {
      float acc = 0.f;
#pragma unroll
      for (int ii = 0; ii < 32; ++ii) acc += wqc[ii] * ar[BCF + ii * 77 + row];
      ar[BQT + row * 32 + t] = acc;
      cfp += ar[BCF + t * 77 + row];
    }
  }
  __syncthreads();   // QT visible; CF reads done -> KB may overwrite

  // ---- phase B2: k,v projection -> KB (over CF), VB ----
  {
    float wkc[32], wvc[32];
#pragma unroll
    for (int ii = 0; ii < 32; ++ii) {
      wkc[ii] = ar[BW + 1056 + ii * 33 + t];
      wvc[ii] = ar[BW + 2112 + ii * 33 + t];
    }
    for (int idx = tid; idx < CC * LL; idx += 256) {
      int o = idx & 31, m = idx >> 5;
      float ka = 0.f, va = 0.f;
#pragma unroll
      for (int ii = 0; ii < 32; ++ii) {
        float x = ar[BKV + ii * 150 + m];
        ka += wkc[ii] * x;
        va += wvc[ii] * x;
      }
      ar[BKB + o * 152 + m] = ka;
      ar[BVB + o * 156 + m] = va;
    }
    if (tid < 64) ar[BVB + (tid >> 1) * 156 + 150 + (tid & 1)] = 0.f;  // PV pad
  }
  __syncthreads();   // KB/VB ready; KV+W dead -> ROWP may overwrite

  // ---- phase D: per-chunk (5 rows) scores -> softmax -> PV ----
  float ms = 0.f;
  const int rbase = BROWP + g * 760;
  const float scale = 0.17677669529663687f;   // 1/sqrt(32)
#pragma unroll 1
  for (int cc = 0; cc < 2; ++cc) {
    const int ch = g + 8 * cc;
    if (ch >= 15) break;
    const int r0 = ch * 5;

    float2 acc[5][3];
#pragma unroll
    for (int i = 0; i < 5; ++i)
#pragma unroll
      for (int u = 0; u < 3; ++u) acc[i][u] = make_float2(0.f, 0.f);

#pragma unroll 1
    for (int c2 = 0; c2 < 32; c2 += 2) {
      float2 q01[5];
#pragma unroll
      for (int i = 0; i < 5; ++i) q01[i] = *(const float2*)&ar[BQT + (r0 + i) * 32 + c2];
      const int cb0 = BKB + c2 * 152 + 2 * t;
      const int cb1 = cb0 + 152;
      float2 ka0 = *(const float2*)&ar[cb0];
      float2 ka1 = *(const float2*)&ar[cb0 + 64];
      float2 ka2 = *(const float2*)&ar[cb0 + 128];
      float2 kb0 = *(const float2*)&ar[cb1];
      float2 kb1 = *(const float2*)&ar[cb1 + 64];
      float2 kb2 = *(const float2*)&ar[cb1 + 128];
#pragma unroll
      for (int i = 0; i < 5; ++i) {
        acc[i][0].x += q01[i].x * ka0.x + q01[i].y * kb0.x;
        acc[i][0].y += q01[i].x * ka0.y + q01[i].y * kb0.y;
        acc[i][1].x += q01[i].x * ka1.x + q01[i].y * kb1.x;
        acc[i][1].y += q01[i].x * ka1.y + q01[i].y * kb1.y;
        acc[i][2].x += q01[i].x * ka2.x + q01[i].y * kb2.x;
        acc[i][2].y += q01[i].x * ka2.y + q01[i].y * kb2.y;
      }
    }

    float inv[5];
#pragma unroll
    for (int i = 0; i < 5; ++i) {
      float s0x = acc[i][0].x * scale, s0y = acc[i][0].y * scale;
      float s1x = acc[i][1].x * scale, s1y = acc[i][1].y * scale;
      float s2x = acc[i][2].x * scale, s2y = acc[i][2].y * scale;
      if (t >= 11) { s2x = -1e30f; s2y = -1e30f; }   // m=128+2t >= 150
      float mx = fmaxf(fmaxf(fmaxf(s0x, s0y), fmaxf(s1x, s1y)), fmaxf(s2x, s2y));
#pragma unroll
      for (int off = 16; off > 0; off >>= 1) mx = fmaxf(mx, __shfl_xor(mx, off, 32));
      float p0x = __expf(s0x - mx), p0y = __expf(s0y - mx);
      float p1x = __expf(s1x - mx), p1y = __expf(s1y - mx);
      float p2x = __expf(s2x - mx), p2y = __expf(s2y - mx);
      float ss = p0x + p0y + p1x + p1y + p2x + p2y;
#pragma unroll
      for (int off = 16; off > 0; off >>= 1) ss += __shfl_xor(ss, off, 32);
      inv[i] = 1.f / ss;
      const int rb = rbase + i * 152 + 2 * t;
      *(float2*)&ar[rb]      = make_float2(p0x, p0y);
      *(float2*)&ar[rb + 64] = make_float2(p1x, p1y);
      if (t <= 11) *(float2*)&ar[rb + 128] = make_float2(p2x, p2y);
    }

    float pv[5] = {0.f, 0.f, 0.f, 0.f, 0.f};
    for (int mq = 0; mq < 38; ++mq) {
      float4 vv = *(const float4*)&ar[BVB + t * 156 + 4 * mq];
#pragma unroll
      for (int i = 0; i < 5; ++i) {
        float4 pp = *(const float4*)&ar[rbase + i * 152 + 4 * mq];
        pv[i] += pp.x * vv.x + pp.y * vv.y + pp.z * vv.z + pp.w * vv.w;
      }
    }
#pragma unroll
    for (int i = 0; i < 5; ++i) ms += pv[i] * inv[i];
  }

  ar[BPART + g * 32 + t] = cfp + ms;
  __syncthreads();

  // ---- epilogue: mean over l, project with wo ----
  if (tid < 32) {
    float tot = 0.f;
#pragma unroll
    for (int gg = 0; gg < 8; ++gg) tot += ar[BPART + gg * 32 + tid];
    ar[BMS + tid] = tot * (1.f / 75.f);
  }
  __syncthreads();
  if (tid < 2) {
    float e = 0.f;
#pragma unroll
    for (int c2 = 0; c2 < CC; ++c2) e += wo[tid * CC + c2] * ar[BMS + c2];
    eout[a * 2 + tid] = e;
  }
}

// ---------------------------------------------------------------------------
// K5: meta head per site (unchanged)
// ---------------------------------------------------------------------------
__global__ __launch_bounds__(64) void k_meta(const float* __restrict__ cfs0,
                                             const float* __restrict__ cfa2,
                                             const float* __restrict__ mw,
                                             const float* __restrict__ mb,
                                             float* __restrict__ mout) {
  __shared__ float feat[64];
  __shared__ float lgt[3];
  const int s = blockIdx.x;
  const int tid = threadIdx.x;
  float f = 0.f;
  if (tid < 32) {
    const float* p = cfs0 + (size_t)s * (CC * LC) + tid * LC;
    for (int l = 0; l < LC; ++l) f += p[l];
  } else {
    const float* p0 = cfa2 + (size_t)(2 * s) * (CC * LC) + (tid - 32) * LC;
    const float* p1 = cfa2 + (size_t)(2 * s + 1) * (CC * LC) + (tid - 32) * LC;
    for (int l = 0; l < LC; ++l) f += p0[l] + p1[l];
  }
  feat[tid] = f * (1.f / 75.f);
  __syncthreads();
  if (tid < 3) {
    float acc2 = mb[tid];
    for (int c2 = 0; c2 < 64; ++c2) acc2 += mw[tid * 64 + c2] * feat[c2];
    lgt[tid] = acc2;
  }
  __syncthreads();
  if (tid < 3) {
    float mx = fmaxf(lgt[0], fmaxf(lgt[1], lgt[2]));
    float e0 = __expf(lgt[0] - mx), e1 = __expf(lgt[1] - mx), e2 = __expf(lgt[2] - mx);
    mout[s * 3 + tid] = __expf(lgt[tid] - mx) / (e0 + e1 + e2);
  }
}

// ---------------------------------------------------------------------------
extern "C" void kernel_launch(void* const* d_in, const int* in_sizes, int n_in,
                              void* d_out, int out_size, void* d_ws, size_t ws_size,
                              hipStream_t stream) {
  const float* t0      = (const float*)d_in[0];
  const float* t1      = (const float*)d_in[1];
  const float* conv0_w = (const float*)d_in[2];
  const float* conv1_w = (const float*)d_in[3];
  const float* comp0_w = (const float*)d_in[4];
  const float* comp1_w = (const float*)d_in[5];
  const float* comp2_w = (const float*)d_in[6];
  const float* xq0 = (const float*)d_in[7];
  const float* xk0 = (const float*)d_in[8];
  const float* xv0 = (const float*)d_in[9];
  const float* xo0 = (const float*)d_in[10];
  const float* xq1 = (const float*)d_in[11];
  const float* xk1 = (const float*)d_in[12];
  const float* xv1 = (const float*)d_in[13];
  const float* xo1 = (const float*)d_in[14];
  const float* xq2 = (const float*)d_in[15];
  const float* xk2 = (const float*)d_in[16];
  const float* xv2 = (const float*)d_in[17];
  const float* xo2 = (const float*)d_in[18];
  const float* comb_w = (const float*)d_in[19];
  const float* meta_w = (const float*)d_in[20];
  const float* meta_b = (const float*)d_in[21];

  float* wsf  = (float*)d_ws;
  float* red0 = wsf;
  float* red1 = red0 + (size_t)NA * CC * LL;
  float* cfa  = red1 + (size_t)NA * CC * LL;
  float* cfs0 = cfa + (size_t)NA * CC * LC;
  float* out  = (float*)d_out;

  k_conv_sum_mfma<<<NA, 256, 0, stream>>>(t0, conv0_w, red0);
  k_conv_sum_mfma<<<NA, 256, 0, stream>>>(t1, conv1_w, red1);

  k_compress2<<<NS, 256, 0, stream>>>(red0, comp0_w, cfa, cfs0);
  k_attn<<<NA, 256, 0, stream>>>(cfa, cfs0, xq0, xk0, xv0, xo0, out + 0);

  k_compress2<<<NS, 256, 0, stream>>>(red1, comp1_w, cfa, cfs0);
  k_attn<<<NA, 256, 0, stream>>>(cfa, cfs0, xq1, xk1, xv1, xo1, out + 2 * NA);

  k_comb<<<NA, 256, 0, stream>>>(red0, red1, comb_w, red0);
  k_compress2<<<NS, 256, 0, stream>>>(red0, comp2_w, cfa, cfs0);
  k_attn<<<NA, 256, 0, stream>>>(cfa, cfs0, xq2, xk2, xv2, xo2, out + 4 * NA);

  k_meta<<<NS, 64, 0, stream>>>(cfs0, cfa, meta_w, meta_b, out + 6 * NA);
}

// Round 12
// 1397.805 us; speedup vs baseline: 1.3090x; 1.0585x over previous
//
#include <hip/hip_runtime.h>
#include <math.h>

#define NS 1024
#define NA 2048
#define CIN 16
#define CC 32
#define LL 150
#define LC 75

typedef __attribute__((ext_vector_type(8))) short short8;
typedef __attribute__((ext_vector_type(4))) float float4v;

__device__ __forceinline__ unsigned short f2bf(float f) {
  // round-to-nearest-even fp32 -> bf16
  unsigned int u = __float_as_uint(f);
  unsigned int r = (u + 0x7FFFu + ((u >> 16) & 1u)) >> 16;
  return (unsigned short)r;
}

__device__ __forceinline__ unsigned int pkbf(float lo, float hi) {
  return (unsigned int)f2bf(lo) | ((unsigned int)f2bf(hi) << 16);
}

// ---------------------------------------------------------------------------
// K1 v7: conv1d(k=5,pad=2) + ReLU + sum over 16 reads (unchanged from R11 —
// line-efficient staging: float2 loads, packed u32 LDS writes, dbuf skeleton).
// ---------------------------------------------------------------------------
__global__ __launch_bounds__(256) void k_conv_sum_mfma(const float* __restrict__ x,
                                                       const float* __restrict__ w,
                                                       float* __restrict__ red) {
  __shared__ unsigned short xs[2][154 * 32];   // 2 x 616 slots of 16B
  const int a = blockIdx.x;
  const int tid = threadIdx.x;
  const int lane = tid & 63;
  const int wv = tid >> 6;

  short8 afr[2][3];
  {
    const int mrow = lane & 15;
    const int h = lane >> 4;
    for (int mt = 0; mt < 2; ++mt) {
      const int c = mt * 16 + mrow;
      for (int s = 0; s < 3; ++s) {
        short8 f;
#pragma unroll
        for (int j = 0; j < 8; ++j) {
          int ic = 4 * h + (j >> 1);
          int tap = 2 * s + (j & 1);
          float wval = (tap < 5) ? w[c * 80 + ic * 5 + tap] : 0.f;
          f[j] = (short)f2bf(wval);
        }
        afr[mt][s] = f;
      }
    }
  }

  float4v sum[2][3];
#pragma unroll
  for (int mt = 0; mt < 2; ++mt)
#pragma unroll
    for (int nt = 0; nt < 3; ++nt) sum[mt][nt] = (float4v)(0.f);

  const int nbase = wv * 48;
  const int nrow = lane & 15;
  const int hh = lane >> 4;
  const float4v zf = (float4v)(0.f);

  auto stage = [&](int r, int buf) {
    const float* xr = x + (size_t)(a * 16 + r) * (CIN * LL);
    unsigned int* xb32 = (unsigned int*)xs[buf];
    for (int idx = tid; idx < 16 * 38; idx += 256) {
      const int ic = idx & 15;
      const int seg = idx >> 4;
      const int l0 = seg * 4;
      const float* row = xr + ic * LL;
      float v0, v1, v2, v3, v4;
      if (seg < 37) {
        float2 u = *(const float2*)(row + l0);
        float2 u2 = *(const float2*)(row + l0 + 2);
        v0 = u.x; v1 = u.y; v2 = u2.x; v3 = u2.y;
        v4 = row[l0 + 4];
      } else {
        float2 u = *(const float2*)(row + 148);
        v0 = u.x; v1 = u.y; v2 = 0.f; v3 = 0.f; v4 = 0.f;
      }
      const int hb = 4 * (ic >> 2) + (ic & 3);
      unsigned int* b32 = xb32 + 16 * (l0 + 2) + hb;
      b32[0]  = pkbf(v0, v1);
      b32[16] = pkbf(v1, v2);
      b32[32] = pkbf(v2, v3);
      b32[48] = pkbf(v3, v4);
    }
    if (tid < 32) {
      const int ic = tid & 15;
      const int which = tid >> 4;
      const int hb = 4 * (ic >> 2) + (ic & 3);
      xb32[16 * which + hb] = which ? pkbf(0.f, xr[ic * LL]) : 0u;
    }
  };

  stage(0, 0);
  __syncthreads();

  for (int r = 0; r < 16; ++r) {
    const int cur = r & 1;
    if (r + 1 < 16) stage(r + 1, cur ^ 1);

    float4v acc[2][3];
#pragma unroll
    for (int s = 0; s < 3; ++s) {
#pragma unroll
      for (int nt = 0; nt < 3; ++nt) {
        int p = nbase + nt * 16 + nrow + 2 * s;
        if (p >= 154) p -= 154;
        short8 bfrag = *(const short8*)&xs[cur][(4 * p + hh) * 8];
#pragma unroll
        for (int mt = 0; mt < 2; ++mt) {
          acc[mt][nt] = __builtin_amdgcn_mfma_f32_16x16x32_bf16(
              afr[mt][s], bfrag, (s == 0) ? zf : acc[mt][nt], 0, 0, 0);
        }
      }
    }
#pragma unroll
    for (int mt = 0; mt < 2; ++mt)
#pragma unroll
      for (int nt = 0; nt < 3; ++nt)
#pragma unroll
        for (int q = 0; q < 4; ++q) sum[mt][nt][q] += fmaxf(acc[mt][nt][q], 0.f);

    __syncthreads();
  }

  const int ccol = lane & 15;
  const int crow4 = (lane >> 4) * 4;
  for (int mt = 0; mt < 2; ++mt)
    for (int nt = 0; nt < 3; ++nt) {
      int l = nbase + nt * 16 + ccol;
      if (l < LL) {
#pragma unroll
        for (int q = 0; q < 4; ++q) {
          int c = mt * 16 + crow4 + q;
          red[(size_t)a * (CC * LL) + c * LL + l] = sum[mt][nt][q];
        }
      }
    }
}

// ---------------------------------------------------------------------------
// K2: red2 = relu(comb_w @ [red0|red1]) in place over red0 (unchanged)
// ---------------------------------------------------------------------------
__global__ __launch_bounds__(256) void k_comb(const float* __restrict__ red0,
                                              const float* __restrict__ red1,
                                              const float* __restrict__ cw,
                                              float* __restrict__ out) {
  __shared__ float ins[64][152];
  __shared__ float cwl[64][CC];
  const int a = blockIdx.x;
  const int tid = threadIdx.x;

  for (int i = tid; i < 64 * CC; i += 256) {
    int c = i & 31; int c2 = i >> 5;
    cwl[c2][c] = cw[c * 64 + c2];
  }
  for (int i = tid; i < CC * LL; i += 256) {
    int c2 = i / LL; int l = i - c2 * LL;
    ins[c2][l] = red0[(size_t)a * (CC * LL) + i];
    ins[32 + c2][l] = red1[(size_t)a * (CC * LL) + i];
  }
  __syncthreads();

  const int c = tid & 31;
  const int lg = tid >> 5;
  const int l0 = lg * 19;
  const int nl = (LL - l0 < 19) ? (LL - l0) : 19;
  float v[19];
#pragma unroll
  for (int j = 0; j < 19; ++j) v[j] = 0.f;
  for (int c2 = 0; c2 < 64; ++c2) {
    float wv = cwl[c2][c];
#pragma unroll
    for (int j = 0; j < 19; ++j) v[j] += wv * ins[c2][l0 + j];
  }
  float* o = out + (size_t)a * (CC * LL) + c * LL + l0;
  for (int j = 0; j < nl; ++j) o[j] = fmaxf(v[j], 0.f);
}

// ---------------------------------------------------------------------------
// K3 v2: per-SITE fused compressor (unchanged from round 7).
// ---------------------------------------------------------------------------
__global__ __launch_bounds__(256) void k_compress2(const float* __restrict__ src,
                                                   const float* __restrict__ w,
                                                   float* __restrict__ cfa,
                                                   float* __restrict__ cfs) {
  __shared__ float ins0[CC][164];
  __shared__ float ins1[CC][164];
  __shared__ float ws[CC][3][CC];
  const int sfull = blockIdx.x;
  const int tid = threadIdx.x;

  for (int i = tid; i < CC * 3 * CC; i += 256) {
    int c = i & 31; int kk = i >> 5; int ic = kk / 3; int t = kk - ic * 3;
    ws[ic][t][c] = w[c * (CC * 3) + ic * 3 + t];
  }
  if (tid < CC) {
    ins0[tid][0] = 0.f; ins0[tid][1] = 0.f; ins0[tid][152] = 0.f; ins0[tid][153] = 0.f;
    ins1[tid][0] = 0.f; ins1[tid][1] = 0.f; ins1[tid][152] = 0.f; ins1[tid][153] = 0.f;
  }
  {
    const float* s0 = src + (size_t)(2 * sfull) * (CC * LL);
    const float* s1 = s0 + CC * LL;
    for (int i = tid; i < CC * LL; i += 256) {
      int ic = i / LL; int l = i - ic * LL;
      ins0[ic][l + 2] = s0[i];
      ins1[ic][l + 2] = s1[i];
    }
  }
  __syncthreads();

  const int c = tid & 31;
  const int jg = tid >> 5;
  const int j0 = jg * 10;
  const int nj = (LC - j0 < 10) ? (LC - j0) : 10;
  float v0[10], v1[10];
#pragma unroll
  for (int j = 0; j < 10; ++j) { v0[j] = 0.f; v1[j] = 0.f; }
  for (int ic = 0; ic < CC; ++ic) {
    float w0 = ws[ic][0][c], w1 = ws[ic][1][c], w2 = ws[ic][2][c];
    float xa[12], xb[12];
#pragma unroll
    for (int i = 0; i < 12; ++i) {
      xa[i] = ins0[ic][2 * j0 + 2 * i];
      xb[i] = ins1[ic][2 * j0 + 2 * i];
    }
#pragma unroll
    for (int j = 0; j < 10; ++j) {
      v0[j] += w0 * xa[j] + w1 * xa[j + 1] + w2 * xa[j + 2];
      v1[j] += w0 * xb[j] + w1 * xb[j + 1] + w2 * xb[j + 2];
    }
  }
  float* oa0 = cfa + (size_t)(2 * sfull) * (CC * LC) + c * LC + j0;
  float* oa1 = oa0 + CC * LC;
  float* os  = cfs + (size_t)sfull * (CC * LC) + c * LC + j0;
  for (int j = 0; j < nj; ++j) {
    float a0 = v0[j], a1 = v1[j];
    oa0[j] = fmaxf(a0, 0.f);
    oa1[j] = fmaxf(a1, 0.f);
    os[j]  = fmaxf(a0 + a1, 0.f);
  }
}

// ---------------------------------------------------------------------------
// K4 v6: per-SITE fused cross-attention, sequential alleles, shared k/v.
// One block per site: k/v projected ONCE (B2 was the LDS-heaviest phase and
// was duplicated per allele in v5); phase A staged once. Allele0 uses CF0 in
// LDS; allele1's B1 reads cfa1 straight from global (L2-hot, broadcast
// addresses) because its LDS slot is aliased away. Phase-D register structure
// is exactly v5's (one 5x3 float2 tile live, unroll-1 chunk loop) -> no
// spill. B2 keeps o = idx&31 == t.
//
// Arena (floats) = 20224 (80896 B) -> 2 blocks/CU:
//  KV   @0     [32][150] = 4800  (dead after B2)
//  WK   @4800  [32][33] = 1056   (dead after B2)
//  WV   @5856  [32][33] = 1056   (dead after B2)
//  WQ   @6912  [32][33] = 1056   (live through B1(1))
//  QT   @7968  [75][32] = 2400   (rewritten per allele)
//  CF0  @10368 [32][77] = 2464   (dead after B1(0))
//  KB   @10368 [32][152] = 4864  (alias CF0; end 15232)
//  VB   @15232 [32][156] = 4992  (end 20224)
//  ROWP @0     [8][5][152] = 6080 (phase D alias over KV+WK+WV-part, dead)
//  PART @6080  [2][8][32] = 512; MS @6592 [2][32] = 64 (end 6656 < 6912)
// ---------------------------------------------------------------------------
#define BKV   0
#define BWK   4800
#define BWV   5856
#define BWQ   6912
#define BQT   7968
#define BCF   10368
#define BKB   10368
#define BVB   15232
#define BROWP 0
#define BPART 6080
#define BMS   6592
#define ARENA 20224

__device__ __forceinline__ void attn_phase_d(float* __restrict__ ar, int g, int t,
                                             float& ms) {
  const float scale = 0.17677669529663687f;   // 1/sqrt(32)
  const int rbase = BROWP + g * 760;
#pragma unroll 1
  for (int cc = 0; cc < 2; ++cc) {
    const int ch = g + 8 * cc;
    if (ch >= 15) break;
    const int r0 = ch * 5;

    float2 acc[5][3];
#pragma unroll
    for (int i = 0; i < 5; ++i)
#pragma unroll
      for (int u = 0; u < 3; ++u) acc[i][u] = make_float2(0.f, 0.f);

#pragma unroll 1
    for (int c2 = 0; c2 < 32; c2 += 2) {
      float2 q01[5];
#pragma unroll
      for (int i = 0; i < 5; ++i) q01[i] = *(const float2*)&ar[BQT + (r0 + i) * 32 + c2];
      const int cb0 = BKB + c2 * 152 + 2 * t;
      const int cb1 = cb0 + 152;
      float2 ka0 = *(const float2*)&ar[cb0];
      float2 ka1 = *(const float2*)&ar[cb0 + 64];
      float2 ka2 = *(const float2*)&ar[cb0 + 128];
      float2 kb0 = *(const float2*)&ar[cb1];
      float2 kb1 = *(const float2*)&ar[cb1 + 64];
      float2 kb2 = *(const float2*)&ar[cb1 + 128];
#pragma unroll
      for (int i = 0; i < 5; ++i) {
        acc[i][0].x += q01[i].x * ka0.x + q01[i].y * kb0.x;
        acc[i][0].y += q01[i].x * ka0.y + q01[i].y * kb0.y;
        acc[i][1].x += q01[i].x * ka1.x + q01[i].y * kb1.x;
        acc[i][1].y += q01[i].x * ka1.y + q01[i].y * kb1.y;
        acc[i][2].x += q01[i].x * ka2.x + q01[i].y * kb2.x;
        acc[i][2].y += q01[i].x * ka2.y + q01[i].y * kb2.y;
      }
    }

    float inv[5];
#pragma unroll
    for (int i = 0; i < 5; ++i) {
      float s0x = acc[i][0].x * scale, s0y = acc[i][0].y * scale;
      float s1x = acc[i][1].x * scale, s1y = acc[i][1].y * scale;
      float s2x = acc[i][2].x * scale, s2y = acc[i][2].y * scale;
      if (t >= 11) { s2x = -1e30f; s2y = -1e30f; }   // m=128+2t >= 150
      float mx = fmaxf(fmaxf(fmaxf(s0x, s0y), fmaxf(s1x, s1y)), fmaxf(s2x, s2y));
#pragma unroll
      for (int off = 16; off > 0; off >>= 1) mx = fmaxf(mx, __shfl_xor(mx, off, 32));
      float p0x = __expf(s0x - mx), p0y = __expf(s0y - mx);
      float p1x = __expf(s1x - mx), p1y = __expf(s1y - mx);
      float p2x = __expf(s2x - mx), p2y = __expf(s2y - mx);
      float ss = p0x + p0y + p1x + p1y + p2x + p2y;
#pragma unroll
      for (int off = 16; off > 0; off >>= 1) ss += __shfl_xor(ss, off, 32);
      inv[i] = 1.f / ss;
      const int rb = rbase + i * 152 + 2 * t;
      *(float2*)&ar[rb]      = make_float2(p0x, p0y);
      *(float2*)&ar[rb + 64] = make_float2(p1x, p1y);
      if (t <= 11) *(float2*)&ar[rb + 128] = make_float2(p2x, p2y);  // t=11 -> zeros at 150,151
    }

    float pv[5] = {0.f, 0.f, 0.f, 0.f, 0.f};
    for (int mq = 0; mq < 38; ++mq) {
      float4 vv = *(const float4*)&ar[BVB + t * 156 + 4 * mq];
#pragma unroll
      for (int i = 0; i < 5; ++i) {
        float4 pp = *(const float4*)&ar[rbase + i * 152 + 4 * mq];
        pv[i] += pp.x * vv.x + pp.y * vv.y + pp.z * vv.z + pp.w * vv.w;
      }
    }
#pragma unroll
    for (int i = 0; i < 5; ++i) ms += pv[i] * inv[i];
  }
}

__global__ __launch_bounds__(256) void k_attn(const float* __restrict__ cfa,
                                              const float* __restrict__ cfs0,
                                              const float* __restrict__ wq,
                                              const float* __restrict__ wk,
                                              const float* __restrict__ wv,
                                              const float* __restrict__ wo,
                                              float* __restrict__ eout) {
  __shared__ float ar[ARENA];
  const int s = blockIdx.x;
  const int tid = threadIdx.x;
  const int g = tid >> 5;
  const int t = tid & 31;

  const float* a0g = cfa + (size_t)(2 * s) * (CC * LC);
  const float* a1g = a0g + CC * LC;

  // ---- phase A: stage weights, kv=[cfs0 | cf0+cf1], CF0 ----
  for (int i = tid; i < CC * CC; i += 256) {
    int o = i >> 5, ii = i & 31;
    ar[BWQ + ii * 33 + o] = wq[i];
    ar[BWK + ii * 33 + o] = wk[i];
    ar[BWV + ii * 33 + o] = wv[i];
  }
  {
    const float* sg = cfs0 + (size_t)s * (CC * LC);
    for (int i = tid; i < CC * LC; i += 256) {
      int c = i / 75, l = i - c * 75;
      float v0 = a0g[i], v1 = a1g[i];
      ar[BKV + c * 150 + l]      = sg[i];
      ar[BKV + c * 150 + 75 + l] = v0 + v1;
      ar[BCF + c * 77 + l]       = v0;
    }
  }
  __syncthreads();

  // ---- B1(0): q0 -> QT, cfsum0 from CF0 ----
  float cfp0 = 0.f;
  {
    float wqc[32];
#pragma unroll
    for (int ii = 0; ii < 32; ++ii) wqc[ii] = ar[BWQ + ii * 33 + t];
    for (int row = g; row < 75; row += 8) {
      float acc = 0.f;
#pragma unroll
      for (int ii = 0; ii < 32; ++ii) acc += wqc[ii] * ar[BCF + ii * 77 + row];
      ar[BQT + row * 32 + t] = acc;
      cfp0 += ar[BCF + t * 77 + row];
    }
  }
  __syncthreads();   // QT0 ready; CF0 reads done -> KB may overwrite

  // ---- B2 (ONCE per site): k,v -> KB, VB ----
  {
    float wkc[32], wvc[32];
#pragma unroll
    for (int ii = 0; ii < 32; ++ii) {
      wkc[ii] = ar[BWK + ii * 33 + t];
      wvc[ii] = ar[BWV + ii * 33 + t];
    }
    for (int idx = tid; idx < CC * LL; idx += 256) {
      int o = idx & 31, m = idx >> 5;   // o == t (stride 256 preserves low 5 bits)
      float ka = 0.f, va = 0.f;
#pragma unroll
      for (int ii = 0; ii < 32; ++ii) {
        float x = ar[BKV + ii * 150 + m];
        ka += wkc[ii] * x;
        va += wvc[ii] * x;
      }
      ar[BKB + o * 152 + m] = ka;
      ar[BVB + o * 156 + m] = va;
    }
    if (tid < 64) ar[BVB + (tid >> 1) * 156 + 150 + (tid & 1)] = 0.f;  // PV pad
  }
  __syncthreads();   // KB/VB ready; KV+WK+WV dead -> ROWP region free

  // ---- D(0): allele0 ----
  float ms0 = 0.f;
  attn_phase_d(ar, g, t, ms0);
  __syncthreads();   // D(0) QT reads done -> B1(1) may rewrite QT

  // ---- B1(1): q1 -> QT from GLOBAL cfa1 (L2-hot), cfsum1 ----
  float cfp1 = 0.f;
  {
    float wqc[32];
#pragma unroll
    for (int ii = 0; ii < 32; ++ii) wqc[ii] = ar[BWQ + ii * 33 + t];
    for (int row = g; row < 75; row += 8) {
      float acc = 0.f;
#pragma unroll
      for (int ii = 0; ii < 32; ++ii) acc += wqc[ii] * a1g[ii * 75 + row];  // broadcast
      ar[BQT + row * 32 + t] = acc;
      cfp1 += a1g[t * 75 + row];
    }
  }
  __syncthreads();   // QT1 ready

  // ---- D(1): allele1 ----
  float ms1 = 0.f;
  attn_phase_d(ar, g, t, ms1);

  ar[BPART + g * 32 + t]       = cfp0 + ms0;
  ar[BPART + 256 + g * 32 + t] = cfp1 + ms1;
  __syncthreads();

  // ---- epilogue: mean over l, project with wo (both alleles) ----
  if (tid < 64) {
    int al = tid >> 5, tt = tid & 31;
    float tot = 0.f;
#pragma unroll
    for (int gg = 0; gg < 8; ++gg) tot += ar[BPART + al * 256 + gg * 32 + tt];
    ar[BMS + al * 32 + tt] = tot * (1.f / 75.f);
  }
  __syncthreads();
  if (tid < 4) {
    int al = tid >> 1, o2 = tid & 1;
    float e = 0.f;
#pragma unroll
    for (int c2 = 0; c2 < CC; ++c2) e += wo[o2 * CC + c2] * ar[BMS + al * 32 + c2];
    eout[s * 4 + tid] = e;   // = eout[(2s+al)*2 + o2]
  }
}

// ---------------------------------------------------------------------------
// K5: meta head per site (unchanged)
// ---------------------------------------------------------------------------
__global__ __launch_bounds__(64) void k_meta(const float* __restrict__ cfs0,
                                             const float* __restrict__ cfa2,
                                             const float* __restrict__ mw,
                                             const float* __restrict__ mb,
                                             float* __restrict__ mout) {
  __shared__ float feat[64];
  __shared__ float lgt[3];
  const int s = blockIdx.x;
  const int tid = threadIdx.x;
  float f = 0.f;
  if (tid < 32) {
    const float* p = cfs0 + (size_t)s * (CC * LC) + tid * LC;
    for (int l = 0; l < LC; ++l) f += p[l];
  } else {
    const float* p0 = cfa2 + (size_t)(2 * s) * (CC * LC) + (tid - 32) * LC;
    const float* p1 = cfa2 + (size_t)(2 * s + 1) * (CC * LC) + (tid - 32) * LC;
    for (int l = 0; l < LC; ++l) f += p0[l] + p1[l];
  }
  feat[tid] = f * (1.f / 75.f);
  __syncthreads();
  if (tid < 3) {
    float acc2 = mb[tid];
    for (int c2 = 0; c2 < 64; ++c2) acc2 += mw[tid * 64 + c2] * feat[c2];
    lgt[tid] = acc2;
  }
  __syncthreads();
  if (tid < 3) {
    float mx = fmaxf(lgt[0], fmaxf(lgt[1], lgt[2]));
    float e0 = __expf(lgt[0] - mx), e1 = __expf(lgt[1] - mx), e2 = __expf(lgt[2] - mx);
    mout[s * 3 + tid] = __expf(lgt[tid] - mx) / (e0 + e1 + e2);
  }
}

// ---------------------------------------------------------------------------
extern "C" void kernel_launch(void* const* d_in, const int* in_sizes, int n_in,
                              void* d_out, int out_size, void* d_ws, size_t ws_size,
                              hipStream_t stream) {
  const float* t0      = (const float*)d_in[0];
  const float* t1      = (const float*)d_in[1];
  const float* conv0_w = (const float*)d_in[2];
  const float* conv1_w = (const float*)d_in[3];
  const float* comp0_w = (const float*)d_in[4];
  const float* comp1_w = (const float*)d_in[5];
  const float* comp2_w = (const float*)d_in[6];
  const float* xq0 = (const float*)d_in[7];
  const float* xk0 = (const float*)d_in[8];
  const float* xv0 = (const float*)d_in[9];
  const float* xo0 = (const float*)d_in[10];
  const float* xq1 = (const float*)d_in[11];
  const float* xk1 = (const float*)d_in[12];
  const float* xv1 = (const float*)d_in[13];
  const float* xo1 = (const float*)d_in[14];
  const float* xq2 = (const float*)d_in[15];
  const float* xk2 = (const float*)d_in[16];
  const float* xv2 = (const float*)d_in[17];
  const float* xo2 = (const float*)d_in[18];
  const float* comb_w = (const float*)d_in[19];
  const float* meta_w = (const float*)d_in[20];
  const float* meta_b = (const float*)d_in[21];

  float* wsf  = (float*)d_ws;
  float* red0 = wsf;
  float* red1 = red0 + (size_t)NA * CC * LL;
  float* cfa  = red1 + (size_t)NA * CC * LL;
  float* cfs0 = cfa + (size_t)NA * CC * LC;
  float* out  = (float*)d_out;

  k_conv_sum_mfma<<<NA, 256, 0, stream>>>(t0, conv0_w, red0);
  k_conv_sum_mfma<<<NA, 256, 0, stream>>>(t1, conv1_w, red1);

  k_compress2<<<NS, 256, 0, stream>>>(red0, comp0_w, cfa, cfs0);
  k_attn<<<NS, 256, 0, stream>>>(cfa, cfs0, xq0, xk0, xv0, xo0, out + 0);

  k_compress2<<<NS, 256, 0, stream>>>(red1, comp1_w, cfa, cfs0);
  k_attn<<<NS, 256, 0, stream>>>(cfa, cfs0, xq1, xk1, xv1, xo1, out + 2 * NA);

  k_comb<<<NA, 256, 0, stream>>>(red0, red1, comb_w, red0);
  k_compress2<<<NS, 256, 0, stream>>>(red0, comp2_w, cfa, cfs0);
  k_attn<<<NS, 256, 0, stream>>>(cfa, cfs0, xq2, xk2, xv2, xo2, out + 4 * NA);

  k_meta<<<NS, 64, 0, stream>>>(cfs0, cfa, meta_w, meta_b, out + 6 * NA);
}

// Round 13
// 1360.952 us; speedup vs baseline: 1.3445x; 1.0271x over previous
//
#include <hip/hip_runtime.h>
#include <math.h>

#define NS 1024
#define NA 2048
#define CIN 16
#define CC 32
#define LL 150
#define LC 75

typedef __attribute__((ext_vector_type(8))) short short8;
typedef __attribute__((ext_vector_type(4))) float float4v;

__device__ __forceinline__ unsigned short f2bf(float f) {
  // round-to-nearest-even fp32 -> bf16
  unsigned int u = __float_as_uint(f);
  unsigned int r = (u + 0x7FFFu + ((u >> 16) & 1u)) >> 16;
  return (unsigned short)r;
}

__device__ __forceinline__ unsigned int pkbf(float lo, float hi) {
  return (unsigned int)f2bf(lo) | ((unsigned int)f2bf(hi) << 16);
}

// ---------------------------------------------------------------------------
// K1 v7: conv1d(k=5,pad=2) + ReLU + sum over 16 reads (unchanged from R11 —
// line-efficient staging: float2 loads, packed u32 LDS writes, dbuf skeleton).
// ---------------------------------------------------------------------------
__global__ __launch_bounds__(256) void k_conv_sum_mfma(const float* __restrict__ x,
                                                       const float* __restrict__ w,
                                                       float* __restrict__ red) {
  __shared__ unsigned short xs[2][154 * 32];   // 2 x 616 slots of 16B
  const int a = blockIdx.x;
  const int tid = threadIdx.x;
  const int lane = tid & 63;
  const int wv = tid >> 6;

  short8 afr[2][3];
  {
    const int mrow = lane & 15;
    const int h = lane >> 4;
    for (int mt = 0; mt < 2; ++mt) {
      const int c = mt * 16 + mrow;
      for (int s = 0; s < 3; ++s) {
        short8 f;
#pragma unroll
        for (int j = 0; j < 8; ++j) {
          int ic = 4 * h + (j >> 1);
          int tap = 2 * s + (j & 1);
          float wval = (tap < 5) ? w[c * 80 + ic * 5 + tap] : 0.f;
          f[j] = (short)f2bf(wval);
        }
        afr[mt][s] = f;
      }
    }
  }

  float4v sum[2][3];
#pragma unroll
  for (int mt = 0; mt < 2; ++mt)
#pragma unroll
    for (int nt = 0; nt < 3; ++nt) sum[mt][nt] = (float4v)(0.f);

  const int nbase = wv * 48;
  const int nrow = lane & 15;
  const int hh = lane >> 4;
  const float4v zf = (float4v)(0.f);

  auto stage = [&](int r, int buf) {
    const float* xr = x + (size_t)(a * 16 + r) * (CIN * LL);
    unsigned int* xb32 = (unsigned int*)xs[buf];
    for (int idx = tid; idx < 16 * 38; idx += 256) {
      const int ic = idx & 15;
      const int seg = idx >> 4;
      const int l0 = seg * 4;
      const float* row = xr + ic * LL;
      float v0, v1, v2, v3, v4;
      if (seg < 37) {
        float2 u = *(const float2*)(row + l0);
        float2 u2 = *(const float2*)(row + l0 + 2);
        v0 = u.x; v1 = u.y; v2 = u2.x; v3 = u2.y;
        v4 = row[l0 + 4];
      } else {
        float2 u = *(const float2*)(row + 148);
        v0 = u.x; v1 = u.y; v2 = 0.f; v3 = 0.f; v4 = 0.f;
      }
      const int hb = 4 * (ic >> 2) + (ic & 3);
      unsigned int* b32 = xb32 + 16 * (l0 + 2) + hb;
      b32[0]  = pkbf(v0, v1);
      b32[16] = pkbf(v1, v2);
      b32[32] = pkbf(v2, v3);
      b32[48] = pkbf(v3, v4);
    }
    if (tid < 32) {
      const int ic = tid & 15;
      const int which = tid >> 4;
      const int hb = 4 * (ic >> 2) + (ic & 3);
      xb32[16 * which + hb] = which ? pkbf(0.f, xr[ic * LL]) : 0u;
    }
  };

  stage(0, 0);
  __syncthreads();

  for (int r = 0; r < 16; ++r) {
    const int cur = r & 1;
    if (r + 1 < 16) stage(r + 1, cur ^ 1);

    float4v acc[2][3];
#pragma unroll
    for (int s = 0; s < 3; ++s) {
#pragma unroll
      for (int nt = 0; nt < 3; ++nt) {
        int p = nbase + nt * 16 + nrow + 2 * s;
        if (p >= 154) p -= 154;
        short8 bfrag = *(const short8*)&xs[cur][(4 * p + hh) * 8];
#pragma unroll
        for (int mt = 0; mt < 2; ++mt) {
          acc[mt][nt] = __builtin_amdgcn_mfma_f32_16x16x32_bf16(
              afr[mt][s], bfrag, (s == 0) ? zf : acc[mt][nt], 0, 0, 0);
        }
      }
    }
#pragma unroll
    for (int mt = 0; mt < 2; ++mt)
#pragma unroll
      for (int nt = 0; nt < 3; ++nt)
#pragma unroll
        for (int q = 0; q < 4; ++q) sum[mt][nt][q] += fmaxf(acc[mt][nt][q], 0.f);

    __syncthreads();
  }

  const int ccol = lane & 15;
  const int crow4 = (lane >> 4) * 4;
  for (int mt = 0; mt < 2; ++mt)
    for (int nt = 0; nt < 3; ++nt) {
      int l = nbase + nt * 16 + ccol;
      if (l < LL) {
#pragma unroll
        for (int q = 0; q < 4; ++q) {
          int c = mt * 16 + crow4 + q;
          red[(size_t)a * (CC * LL) + c * LL + l] = sum[mt][nt][q];
        }
      }
    }
}

// ---------------------------------------------------------------------------
// K2: red2 = relu(comb_w @ [red0|red1]) in place over red0 (unchanged)
// ---------------------------------------------------------------------------
__global__ __launch_bounds__(256) void k_comb(const float* __restrict__ red0,
                                              const float* __restrict__ red1,
                                              const float* __restrict__ cw,
                                              float* __restrict__ out) {
  __shared__ float ins[64][152];
  __shared__ float cwl[64][CC];
  const int a = blockIdx.x;
  const int tid = threadIdx.x;

  for (int i = tid; i < 64 * CC; i += 256) {
    int c = i & 31; int c2 = i >> 5;
    cwl[c2][c] = cw[c * 64 + c2];
  }
  for (int i = tid; i < CC * LL; i += 256) {
    int c2 = i / LL; int l = i - c2 * LL;
    ins[c2][l] = red0[(size_t)a * (CC * LL) + i];
    ins[32 + c2][l] = red1[(size_t)a * (CC * LL) + i];
  }
  __syncthreads();

  const int c = tid & 31;
  const int lg = tid >> 5;
  const int l0 = lg * 19;
  const int nl = (LL - l0 < 19) ? (LL - l0) : 19;
  float v[19];
#pragma unroll
  for (int j = 0; j < 19; ++j) v[j] = 0.f;
  for (int c2 = 0; c2 < 64; ++c2) {
    float wv = cwl[c2][c];
#pragma unroll
    for (int j = 0; j < 19; ++j) v[j] += wv * ins[c2][l0 + j];
  }
  float* o = out + (size_t)a * (CC * LL) + c * LL + l0;
  for (int j = 0; j < nl; ++j) o[j] = fmaxf(v[j], 0.f);
}

// ---------------------------------------------------------------------------
// K4 v7 "k_cattn": FUSED per-site compressor + cross-attention.
// Compress phase (compress2 logic) computes pre-relu v0/v1 in registers, then
// writes results DIRECTLY into the attn arena (KV = [cfs | relu0+relu1],
// CF0 = relu0) — no global round-trip, no phase-A re-staging. cfa1 -> global
// always (allele1 B1 reads it back, same pattern as v6; first-touch read
// after barrier/vmcnt-drain). cfa0+cfs -> global only when wg (stream 2,
// k_meta consumer). Attn phases are verbatim v6 (proven): B1(0), B2 once,
// D(0), B1(1) from global, D(1), epilogue.
//
// Arena (floats) = 20224 (80896 B) -> 2 blocks/CU. Attn-phase layout = v6:
//  KV@0 WK@4800 WV@5856 WQ@6912 QT@7968 CF0@10368 KB=CF0 VB@15232
//  ROWP@0 PART@6080 MS@6592
// Compress-phase aliases (all dead before attn weights/outputs land):
//  FIN0@0 [32][164]=5248, FIN1@5248, FWS@10496 [96][32]=3072 (ends 13568)
// ---------------------------------------------------------------------------
#define BKV   0
#define BWK   4800
#define BWV   5856
#define BWQ   6912
#define BQT   7968
#define BCF   10368
#define BKB   10368
#define BVB   15232
#define BROWP 0
#define BPART 6080
#define BMS   6592
#define ARENA 20224
#define FIN0  0
#define FIN1  5248
#define FWS   10496

__device__ __forceinline__ void attn_phase_d(float* __restrict__ ar, int g, int t,
                                             float& ms) {
  const float scale = 0.17677669529663687f;   // 1/sqrt(32)
  const int rbase = BROWP + g * 760;
#pragma unroll 1
  for (int cc = 0; cc < 2; ++cc) {
    const int ch = g + 8 * cc;
    if (ch >= 15) break;
    const int r0 = ch * 5;

    float2 acc[5][3];
#pragma unroll
    for (int i = 0; i < 5; ++i)
#pragma unroll
      for (int u = 0; u < 3; ++u) acc[i][u] = make_float2(0.f, 0.f);

#pragma unroll 1
    for (int c2 = 0; c2 < 32; c2 += 2) {
      float2 q01[5];
#pragma unroll
      for (int i = 0; i < 5; ++i) q01[i] = *(const float2*)&ar[BQT + (r0 + i) * 32 + c2];
      const int cb0 = BKB + c2 * 152 + 2 * t;
      const int cb1 = cb0 + 152;
      float2 ka0 = *(const float2*)&ar[cb0];
      float2 ka1 = *(const float2*)&ar[cb0 + 64];
      float2 ka2 = *(const float2*)&ar[cb0 + 128];
      float2 kb0 = *(const float2*)&ar[cb1];
      float2 kb1 = *(const float2*)&ar[cb1 + 64];
      float2 kb2 = *(const float2*)&ar[cb1 + 128];
#pragma unroll
      for (int i = 0; i < 5; ++i) {
        acc[i][0].x += q01[i].x * ka0.x + q01[i].y * kb0.x;
        acc[i][0].y += q01[i].x * ka0.y + q01[i].y * kb0.y;
        acc[i][1].x += q01[i].x * ka1.x + q01[i].y * kb1.x;
        acc[i][1].y += q01[i].x * ka1.y + q01[i].y * kb1.y;
        acc[i][2].x += q01[i].x * ka2.x + q01[i].y * kb2.x;
        acc[i][2].y += q01[i].x * ka2.y + q01[i].y * kb2.y;
      }
    }

    float inv[5];
#pragma unroll
    for (int i = 0; i < 5; ++i) {
      float s0x = acc[i][0].x * scale, s0y = acc[i][0].y * scale;
      float s1x = acc[i][1].x * scale, s1y = acc[i][1].y * scale;
      float s2x = acc[i][2].x * scale, s2y = acc[i][2].y * scale;
      if (t >= 11) { s2x = -1e30f; s2y = -1e30f; }   // m=128+2t >= 150
      float mx = fmaxf(fmaxf(fmaxf(s0x, s0y), fmaxf(s1x, s1y)), fmaxf(s2x, s2y));
#pragma unroll
      for (int off = 16; off > 0; off >>= 1) mx = fmaxf(mx, __shfl_xor(mx, off, 32));
      float p0x = __expf(s0x - mx), p0y = __expf(s0y - mx);
      float p1x = __expf(s1x - mx), p1y = __expf(s1y - mx);
      float p2x = __expf(s2x - mx), p2y = __expf(s2y - mx);
      float ss = p0x + p0y + p1x + p1y + p2x + p2y;
#pragma unroll
      for (int off = 16; off > 0; off >>= 1) ss += __shfl_xor(ss, off, 32);
      inv[i] = 1.f / ss;
      const int rb = rbase + i * 152 + 2 * t;
      *(float2*)&ar[rb]      = make_float2(p0x, p0y);
      *(float2*)&ar[rb + 64] = make_float2(p1x, p1y);
      if (t <= 11) *(float2*)&ar[rb + 128] = make_float2(p2x, p2y);  // t=11 -> zeros at 150,151
    }

    float pv[5] = {0.f, 0.f, 0.f, 0.f, 0.f};
    for (int mq = 0; mq < 38; ++mq) {
      float4 vv = *(const float4*)&ar[BVB + t * 156 + 4 * mq];
#pragma unroll
      for (int i = 0; i < 5; ++i) {
        float4 pp = *(const float4*)&ar[rbase + i * 152 + 4 * mq];
        pv[i] += pp.x * vv.x + pp.y * vv.y + pp.z * vv.z + pp.w * vv.w;
      }
    }
#pragma unroll
    for (int i = 0; i < 5; ++i) ms += pv[i] * inv[i];
  }
}

__global__ __launch_bounds__(256) void k_cattn(const float* __restrict__ red,
                                               const float* __restrict__ cw,
                                               const float* __restrict__ wq,
                                               const float* __restrict__ wk,
                                               const float* __restrict__ wv,
                                               const float* __restrict__ wo,
                                               float* __restrict__ cfa,
                                               float* __restrict__ cfs,
                                               float* __restrict__ eout,
                                               int wg) {
  __shared__ float ar[ARENA];
  const int s = blockIdx.x;
  const int tid = threadIdx.x;
  const int g = tid >> 5;
  const int t = tid & 31;

  float* a0g = cfa + (size_t)(2 * s) * (CC * LC);
  float* a1g = a0g + CC * LC;
  float* sgw = cfs + (size_t)s * (CC * LC);

  // ---- phase C1: stage comp weights + red pair into FIN0/FIN1/FWS ----
  for (int i = tid; i < CC * 3 * CC; i += 256) {
    int c = i & 31; int kk = i >> 5;
    ar[FWS + kk * 32 + c] = cw[c * (CC * 3) + kk];
  }
  if (tid < CC) {
    ar[FIN0 + tid * 164 + 0] = 0.f; ar[FIN0 + tid * 164 + 1] = 0.f;
    ar[FIN0 + tid * 164 + 152] = 0.f; ar[FIN0 + tid * 164 + 153] = 0.f;
    ar[FIN1 + tid * 164 + 0] = 0.f; ar[FIN1 + tid * 164 + 1] = 0.f;
    ar[FIN1 + tid * 164 + 152] = 0.f; ar[FIN1 + tid * 164 + 153] = 0.f;
  }
  {
    const float* s0 = red + (size_t)(2 * s) * (CC * LL);
    const float* s1 = s0 + CC * LL;
    for (int i = tid; i < CC * LL; i += 256) {
      int ic = i / LL; int l = i - ic * LL;
      ar[FIN0 + ic * 164 + l + 2] = s0[i];
      ar[FIN1 + ic * 164 + l + 2] = s1[i];
    }
  }
  __syncthreads();

  // ---- phase C2: compress conv into registers (pre-relu v0, v1) ----
  const int j0 = g * 10;
  const int nj = (LC - j0 < 10) ? (LC - j0) : 10;
  float v0[10], v1[10];
#pragma unroll
  for (int j = 0; j < 10; ++j) { v0[j] = 0.f; v1[j] = 0.f; }
  for (int ic = 0; ic < CC; ++ic) {
    float w0 = ar[FWS + (ic * 3 + 0) * 32 + t];
    float w1 = ar[FWS + (ic * 3 + 1) * 32 + t];
    float w2 = ar[FWS + (ic * 3 + 2) * 32 + t];
    float xa[12], xb[12];
#pragma unroll
    for (int i = 0; i < 12; ++i) {
      xa[i] = ar[FIN0 + ic * 164 + 2 * j0 + 2 * i];
      xb[i] = ar[FIN1 + ic * 164 + 2 * j0 + 2 * i];
    }
#pragma unroll
    for (int j = 0; j < 10; ++j) {
      v0[j] += w0 * xa[j] + w1 * xa[j + 1] + w2 * xa[j + 2];
      v1[j] += w0 * xb[j] + w1 * xb[j + 1] + w2 * xb[j + 2];
    }
  }
  __syncthreads();   // all FIN/FWS reads done -> arena may be re-laid

  // ---- phase C3: write outputs into arena (+globals), stage attn weights ---
  for (int j = 0; j < nj; ++j) {
    const int jj = j0 + j;
    float r0 = fmaxf(v0[j], 0.f);
    float r1 = fmaxf(v1[j], 0.f);
    float cs = fmaxf(v0[j] + v1[j], 0.f);
    ar[BKV + t * 150 + jj]      = cs;        // kv first half  = cfs
    ar[BKV + t * 150 + 75 + jj] = r0 + r1;   // kv second half = cfa0+cfa1
    ar[BCF + t * 77 + jj]       = r0;        // CF0 = cfa0
    a1g[t * 75 + jj] = r1;                   // cfa1 -> global (B1(1) readback)
    if (wg) {
      a0g[t * 75 + jj] = r0;                 // for k_meta
      sgw[t * 75 + jj] = cs;
    }
  }
  for (int i = tid; i < CC * CC; i += 256) {
    int o = i >> 5, ii = i & 31;
    ar[BWQ + ii * 33 + o] = wq[i];
    ar[BWK + ii * 33 + o] = wk[i];
    ar[BWV + ii * 33 + o] = wv[i];
  }
  __syncthreads();

  // ---- B1(0): q0 -> QT, cfsum0 from CF0 ----
  float cfp0 = 0.f;
  {
    float wqc[32];
#pragma unroll
    for (int ii = 0; ii < 32; ++ii) wqc[ii] = ar[BWQ + ii * 33 + t];
    for (int row = g; row < 75; row += 8) {
      float acc = 0.f;
#pragma unroll
      for (int ii = 0; ii < 32; ++ii) acc += wqc[ii] * ar[BCF + ii * 77 + row];
      ar[BQT + row * 32 + t] = acc;
      cfp0 += ar[BCF + t * 77 + row];
    }
  }
  __syncthreads();   // QT0 ready; CF0 reads done -> KB may overwrite

  // ---- B2 (ONCE per site): k,v -> KB, VB ----
  {
    float wkc[32], wvc[32];
#pragma unroll
    for (int ii = 0; ii < 32; ++ii) {
      wkc[ii] = ar[BWK + ii * 33 + t];
      wvc[ii] = ar[BWV + ii * 33 + t];
    }
    for (int idx = tid; idx < CC * LL; idx += 256) {
      int o = idx & 31, m = idx >> 5;   // o == t (stride 256 preserves low 5 bits)
      float ka = 0.f, va = 0.f;
#pragma unroll
      for (int ii = 0; ii < 32; ++ii) {
        float x = ar[BKV + ii * 150 + m];
        ka += wkc[ii] * x;
        va += wvc[ii] * x;
      }
      ar[BKB + o * 152 + m] = ka;
      ar[BVB + o * 156 + m] = va;
    }
    if (tid < 64) ar[BVB + (tid >> 1) * 156 + 150 + (tid & 1)] = 0.f;  // PV pad
  }
  __syncthreads();   // KB/VB ready; KV+WK+WV dead -> ROWP region free

  // ---- D(0): allele0 ----
  float ms0 = 0.f;
  attn_phase_d(ar, g, t, ms0);
  __syncthreads();   // D(0) QT reads done -> B1(1) may rewrite QT

  // ---- B1(1): q1 -> QT from GLOBAL cfa1 (L2-hot), cfsum1 ----
  float cfp1 = 0.f;
  {
    float wqc[32];
#pragma unroll
    for (int ii = 0; ii < 32; ++ii) wqc[ii] = ar[BWQ + ii * 33 + t];
    for (int row = g; row < 75; row += 8) {
      float acc = 0.f;
#pragma unroll
      for (int ii = 0; ii < 32; ++ii) acc += wqc[ii] * a1g[ii * 75 + row];  // broadcast
      ar[BQT + row * 32 + t] = acc;
      cfp1 += a1g[t * 75 + row];
    }
  }
  __syncthreads();   // QT1 ready

  // ---- D(1): allele1 ----
  float ms1 = 0.f;
  attn_phase_d(ar, g, t, ms1);

  ar[BPART + g * 32 + t]       = cfp0 + ms0;
  ar[BPART + 256 + g * 32 + t] = cfp1 + ms1;
  __syncthreads();

  // ---- epilogue: mean over l, project with wo (both alleles) ----
  if (tid < 64) {
    int al = tid >> 5, tt = tid & 31;
    float tot = 0.f;
#pragma unroll
    for (int gg = 0; gg < 8; ++gg) tot += ar[BPART + al * 256 + gg * 32 + tt];
    ar[BMS + al * 32 + tt] = tot * (1.f / 75.f);
  }
  __syncthreads();
  if (tid < 4) {
    int al = tid >> 1, o2 = tid & 1;
    float e = 0.f;
#pragma unroll
    for (int c2 = 0; c2 < CC; ++c2) e += wo[o2 * CC + c2] * ar[BMS + al * 32 + c2];
    eout[s * 4 + tid] = e;   // = eout[(2s+al)*2 + o2]
  }
}

// ---------------------------------------------------------------------------
// K5: meta head per site (unchanged)
// ---------------------------------------------------------------------------
__global__ __launch_bounds__(64) void k_meta(const float* __restrict__ cfs0,
                                             const float* __restrict__ cfa2,
                                             const float* __restrict__ mw,
                                             const float* __restrict__ mb,
                                             float* __restrict__ mout) {
  __shared__ float feat[64];
  __shared__ float lgt[3];
  const int s = blockIdx.x;
  const int tid = threadIdx.x;
  float f = 0.f;
  if (tid < 32) {
    const float* p = cfs0 + (size_t)s * (CC * LC) + tid * LC;
    for (int l = 0; l < LC; ++l) f += p[l];
  } else {
    const float* p0 = cfa2 + (size_t)(2 * s) * (CC * LC) + (tid - 32) * LC;
    const float* p1 = cfa2 + (size_t)(2 * s + 1) * (CC * LC) + (tid - 32) * LC;
    for (int l = 0; l < LC; ++l) f += p0[l] + p1[l];
  }
  feat[tid] = f * (1.f / 75.f);
  __syncthreads();
  if (tid < 3) {
    float acc2 = mb[tid];
    for (int c2 = 0; c2 < 64; ++c2) acc2 += mw[tid * 64 + c2] * feat[c2];
    lgt[tid] = acc2;
  }
  __syncthreads();
  if (tid < 3) {
    float mx = fmaxf(lgt[0], fmaxf(lgt[1], lgt[2]));
    float e0 = __expf(lgt[0] - mx), e1 = __expf(lgt[1] - mx), e2 = __expf(lgt[2] - mx);
    mout[s * 3 + tid] = __expf(lgt[tid] - mx) / (e0 + e1 + e2);
  }
}

// ---------------------------------------------------------------------------
extern "C" void kernel_launch(void* const* d_in, const int* in_sizes, int n_in,
                              void* d_out, int out_size, void* d_ws, size_t ws_size,
                              hipStream_t stream) {
  const float* t0      = (const float*)d_in[0];
  const float* t1      = (const float*)d_in[1];
  const float* conv0_w = (const float*)d_in[2];
  const float* conv1_w = (const float*)d_in[3];
  const float* comp0_w = (const float*)d_in[4];
  const float* comp1_w = (const float*)d_in[5];
  const float* comp2_w = (const float*)d_in[6];
  const float* xq0 = (const float*)d_in[7];
  const float* xk0 = (const float*)d_in[8];
  const float* xv0 = (const float*)d_in[9];
  const float* xo0 = (const float*)d_in[10];
  const float* xq1 = (const float*)d_in[11];
  const float* xk1 = (const float*)d_in[12];
  const float* xv1 = (const float*)d_in[13];
  const float* xo1 = (const float*)d_in[14];
  const float* xq2 = (const float*)d_in[15];
  const float* xk2 = (const float*)d_in[16];
  const float* xv2 = (const float*)d_in[17];
  const float* xo2 = (const float*)d_in[18];
  const float* comb_w = (const float*)d_in[19];
  const float* meta_w = (const float*)d_in[20];
  const float* meta_b = (const float*)d_in[21];

  float* wsf  = (float*)d_ws;
  float* red0 = wsf;
  float* red1 = red0 + (size_t)NA * CC * LL;
  float* cfa  = red1 + (size_t)NA * CC * LL;
  float* cfs0 = cfa + (size_t)NA * CC * LC;
  float* out  = (float*)d_out;

  k_conv_sum_mfma<<<NA, 256, 0, stream>>>(t0, conv0_w, red0);
  k_conv_sum_mfma<<<NA, 256, 0, stream>>>(t1, conv1_w, red1);

  k_cattn<<<NS, 256, 0, stream>>>(red0, comp0_w, xq0, xk0, xv0, xo0,
                                  cfa, cfs0, out + 0, 0);
  k_cattn<<<NS, 256, 0, stream>>>(red1, comp1_w, xq1, xk1, xv1, xo1,
                                  cfa, cfs0, out + 2 * NA, 0);

  k_comb<<<NA, 256, 0, stream>>>(red0, red1, comb_w, red0);
  k_cattn<<<NS, 256, 0, stream>>>(red0, comp2_w, xq2, xk2, xv2, xo2,
                                  cfa, cfs0, out + 4 * NA, 1);

  k_meta<<<NS, 64, 0, stream>>>(cfs0, cfa, meta_w, meta_b, out + 6 * NA);
}

// Round 14
// 1231.246 us; speedup vs baseline: 1.4861x; 1.1053x over previous
//
#include <hip/hip_runtime.h>
#include <math.h>

#define NS 1024
#define NA 2048
#define CIN 16
#define CC 32
#define LL 150
#define LC 75

typedef __attribute__((ext_vector_type(8))) short short8;
typedef __attribute__((ext_vector_type(4))) float float4v;

__device__ __forceinline__ unsigned short f2bf(float f) {
  // round-to-nearest-even fp32 -> bf16
  unsigned int u = __float_as_uint(f);
  unsigned int r = (u + 0x7FFFu + ((u >> 16) & 1u)) >> 16;
  return (unsigned short)r;
}

__device__ __forceinline__ unsigned int pkbf(float lo, float hi) {
  return (unsigned int)f2bf(lo) | ((unsigned int)f2bf(hi) << 16);
}

__device__ __forceinline__ float bflo(unsigned int u) { return __uint_as_float(u << 16); }
__device__ __forceinline__ float bfhi(unsigned int u) { return __uint_as_float(u & 0xffff0000u); }

// 2x bf16 MAC with f32 accumulate. HW v_dot2_f32_bf16 when available;
// unpack fallback otherwise (compile-time safe).
#if __has_builtin(__builtin_amdgcn_fdot2_f32_bf16)
typedef __attribute__((ext_vector_type(2))) __bf16 bf16x2;
__device__ __forceinline__ float bdot2(unsigned int a, unsigned int b, float c) {
  return __builtin_amdgcn_fdot2_f32_bf16(__builtin_bit_cast(bf16x2, a),
                                         __builtin_bit_cast(bf16x2, b), c, false);
}
#else
__device__ __forceinline__ float bdot2(unsigned int a, unsigned int b, float c) {
  return c + bflo(a) * bflo(b) + bfhi(a) * bfhi(b);
}
#endif

// ---------------------------------------------------------------------------
// K1 v7: conv1d(k=5,pad=2) + ReLU + sum over 16 reads (unchanged from R11).
// ---------------------------------------------------------------------------
__global__ __launch_bounds__(256) void k_conv_sum_mfma(const float* __restrict__ x,
                                                       const float* __restrict__ w,
                                                       float* __restrict__ red) {
  __shared__ unsigned short xs[2][154 * 32];   // 2 x 616 slots of 16B
  const int a = blockIdx.x;
  const int tid = threadIdx.x;
  const int lane = tid & 63;
  const int wv = tid >> 6;

  short8 afr[2][3];
  {
    const int mrow = lane & 15;
    const int h = lane >> 4;
    for (int mt = 0; mt < 2; ++mt) {
      const int c = mt * 16 + mrow;
      for (int s = 0; s < 3; ++s) {
        short8 f;
#pragma unroll
        for (int j = 0; j < 8; ++j) {
          int ic = 4 * h + (j >> 1);
          int tap = 2 * s + (j & 1);
          float wval = (tap < 5) ? w[c * 80 + ic * 5 + tap] : 0.f;
          f[j] = (short)f2bf(wval);
        }
        afr[mt][s] = f;
      }
    }
  }

  float4v sum[2][3];
#pragma unroll
  for (int mt = 0; mt < 2; ++mt)
#pragma unroll
    for (int nt = 0; nt < 3; ++nt) sum[mt][nt] = (float4v)(0.f);

  const int nbase = wv * 48;
  const int nrow = lane & 15;
  const int hh = lane >> 4;
  const float4v zf = (float4v)(0.f);

  auto stage = [&](int r, int buf) {
    const float* xr = x + (size_t)(a * 16 + r) * (CIN * LL);
    unsigned int* xb32 = (unsigned int*)xs[buf];
    for (int idx = tid; idx < 16 * 38; idx += 256) {
      const int ic = idx & 15;
      const int seg = idx >> 4;
      const int l0 = seg * 4;
      const float* row = xr + ic * LL;
      float v0, v1, v2, v3, v4;
      if (seg < 37) {
        float2 u = *(const float2*)(row + l0);
        float2 u2 = *(const float2*)(row + l0 + 2);
        v0 = u.x; v1 = u.y; v2 = u2.x; v3 = u2.y;
        v4 = row[l0 + 4];
      } else {
        float2 u = *(const float2*)(row + 148);
        v0 = u.x; v1 = u.y; v2 = 0.f; v3 = 0.f; v4 = 0.f;
      }
      const int hb = 4 * (ic >> 2) + (ic & 3);
      unsigned int* b32 = xb32 + 16 * (l0 + 2) + hb;
      b32[0]  = pkbf(v0, v1);
      b32[16] = pkbf(v1, v2);
      b32[32] = pkbf(v2, v3);
      b32[48] = pkbf(v3, v4);
    }
    if (tid < 32) {
      const int ic = tid & 15;
      const int which = tid >> 4;
      const int hb = 4 * (ic >> 2) + (ic & 3);
      xb32[16 * which + hb] = which ? pkbf(0.f, xr[ic * LL]) : 0u;
    }
  };

  stage(0, 0);
  __syncthreads();

  for (int r = 0; r < 16; ++r) {
    const int cur = r & 1;
    if (r + 1 < 16) stage(r + 1, cur ^ 1);

    float4v acc[2][3];
#pragma unroll
    for (int s = 0; s < 3; ++s) {
#pragma unroll
      for (int nt = 0; nt < 3; ++nt) {
        int p = nbase + nt * 16 + nrow + 2 * s;
        if (p >= 154) p -= 154;
        short8 bfrag = *(const short8*)&xs[cur][(4 * p + hh) * 8];
#pragma unroll
        for (int mt = 0; mt < 2; ++mt) {
          acc[mt][nt] = __builtin_amdgcn_mfma_f32_16x16x32_bf16(
              afr[mt][s], bfrag, (s == 0) ? zf : acc[mt][nt], 0, 0, 0);
        }
      }
    }
#pragma unroll
    for (int mt = 0; mt < 2; ++mt)
#pragma unroll
      for (int nt = 0; nt < 3; ++nt)
#pragma unroll
        for (int q = 0; q < 4; ++q) sum[mt][nt][q] += fmaxf(acc[mt][nt][q], 0.f);

    __syncthreads();
  }

  const int ccol = lane & 15;
  const int crow4 = (lane >> 4) * 4;
  for (int mt = 0; mt < 2; ++mt)
    for (int nt = 0; nt < 3; ++nt) {
      int l = nbase + nt * 16 + ccol;
      if (l < LL) {
#pragma unroll
        for (int q = 0; q < 4; ++q) {
          int c = mt * 16 + crow4 + q;
          red[(size_t)a * (CC * LL) + c * LL + l] = sum[mt][nt][q];
        }
      }
    }
}

// ---------------------------------------------------------------------------
// K2: red2 = relu(comb_w @ [red0|red1]) in place over red0 (unchanged)
// ---------------------------------------------------------------------------
__global__ __launch_bounds__(256) void k_comb(const float* __restrict__ red0,
                                              const float* __restrict__ red1,
                                              const float* __restrict__ cw,
                                              float* __restrict__ out) {
  __shared__ float ins[64][152];
  __shared__ float cwl[64][CC];
  const int a = blockIdx.x;
  const int tid = threadIdx.x;

  for (int i = tid; i < 64 * CC; i += 256) {
    int c = i & 31; int c2 = i >> 5;
    cwl[c2][c] = cw[c * 64 + c2];
  }
  for (int i = tid; i < CC * LL; i += 256) {
    int c2 = i / LL; int l = i - c2 * LL;
    ins[c2][l] = red0[(size_t)a * (CC * LL) + i];
    ins[32 + c2][l] = red1[(size_t)a * (CC * LL) + i];
  }
  __syncthreads();

  const int c = tid & 31;
  const int lg = tid >> 5;
  const int l0 = lg * 19;
  const int nl = (LL - l0 < 19) ? (LL - l0) : 19;
  float v[19];
#pragma unroll
  for (int j = 0; j < 19; ++j) v[j] = 0.f;
  for (int c2 = 0; c2 < 64; ++c2) {
    float wv = cwl[c2][c];
#pragma unroll
    for (int j = 0; j < 19; ++j) v[j] += wv * ins[c2][l0 + j];
  }
  float* o = out + (size_t)a * (CC * LL) + c * LL + l0;
  for (int j = 0; j < nl; ++j) o[j] = fmaxf(v[j], 0.f);
}

// ---------------------------------------------------------------------------
// K4 v8 "k_cattn": fused per-site compressor + cross-attention, bf16 LDS.
// vs v7: KV (transposed [m][c]), K, V, P stored bf16 in LDS -> arena shrinks
// 80.9 KB -> 52224 B -> 3 blocks/CU (+50% resident waves; the kernel was
// 49% stall at 2 blocks). B2 and PV use v_dot2_f32_bf16 (2 MACs/instr, f32
// accum) so the bf16 versions cost FEWER VALU ops than fp32; only the score
// loop pays unpack (+~700 ops). q/QT/CF0 stay fp32. Math/masking identical.
//
// Arena = 13056 floats (52224 B). Float offsets:
//  AKVt(bf16 [150][32]us) @0 (=2400 fl)   | compress: FIN0@0 [32][156]
//  WK @2400, WV @3456, WQ @4512 (33-pad)  |           FIN1@4992 [32][156]
//  QT @5568 [75][32] fp32                 |           FWS @9984 [96][32]
//  CF0 @7968 [32][77] fp32 (dead after B1(0)); KBb(bf16 [32][154]us) aliases
//  VBb(bf16 [32][164]us) @10432 (=2624 fl, end 13056)
//  ROWPb(bf16 [8][5][152]us) @0 (3040 fl, aliases dead AKVt+WK)
//  PART @3456 [2][8][32], MS @3968 (alias dead WV)
// Bank maps: KBb score-reads word-stride 77 (CF); VBb reads/writes 2-way
// (free); AKVt/QT/ROWP writes stride-1 (CF); q/p PV reads broadcast.
// ---------------------------------------------------------------------------
#define BWK   2400
#define BWV   3456
#define BWQ   4512
#define BQT   5568
#define BCF   7968
#define KB_US 15936     // = BCF*2 (ushort index)
#define VB_US 20864     // = 10432*2
#define BPART 3456
#define BMS   3968
#define ARENA 13056
#define FIN0  0
#define FIN1  4992
#define FWS   9984

__device__ __forceinline__ void attn_phase_d(float* __restrict__ ar, int g, int t,
                                             float& ms) {
  unsigned short* aru = (unsigned short*)ar;
  const float scale = 0.17677669529663687f;   // 1/sqrt(32)
  const int rb_us = g * 760;                  // ROWPb group base (ushorts)
#pragma unroll 1
  for (int cc = 0; cc < 2; ++cc) {
    const int ch = g + 8 * cc;
    if (ch >= 15) break;
    const int r0 = ch * 5;

    float2 acc[5][3];
#pragma unroll
    for (int i = 0; i < 5; ++i)
#pragma unroll
      for (int u = 0; u < 3; ++u) acc[i][u] = make_float2(0.f, 0.f);

#pragma unroll 1
    for (int c2 = 0; c2 < 32; c2 += 2) {
      float2 q01[5];
#pragma unroll
      for (int i = 0; i < 5; ++i) q01[i] = *(const float2*)&ar[BQT + (r0 + i) * 32 + c2];
      const int k0 = KB_US + c2 * 154 + 2 * t;
      const int k1 = k0 + 154;
      unsigned int a0 = *(const unsigned int*)&aru[k0];
      unsigned int a1 = *(const unsigned int*)&aru[k0 + 64];
      unsigned int a2 = *(const unsigned int*)&aru[k0 + 128];
      unsigned int b0 = *(const unsigned int*)&aru[k1];
      unsigned int b1 = *(const unsigned int*)&aru[k1 + 64];
      unsigned int b2 = *(const unsigned int*)&aru[k1 + 128];
      float ka0x = bflo(a0), ka0y = bfhi(a0);
      float ka1x = bflo(a1), ka1y = bfhi(a1);
      float ka2x = bflo(a2), ka2y = bfhi(a2);
      float kb0x = bflo(b0), kb0y = bfhi(b0);
      float kb1x = bflo(b1), kb1y = bfhi(b1);
      float kb2x = bflo(b2), kb2y = bfhi(b2);
#pragma unroll
      for (int i = 0; i < 5; ++i) {
        acc[i][0].x += q01[i].x * ka0x + q01[i].y * kb0x;
        acc[i][0].y += q01[i].x * ka0y + q01[i].y * kb0y;
        acc[i][1].x += q01[i].x * ka1x + q01[i].y * kb1x;
        acc[i][1].y += q01[i].x * ka1y + q01[i].y * kb1y;
        acc[i][2].x += q01[i].x * ka2x + q01[i].y * kb2x;
        acc[i][2].y += q01[i].x * ka2y + q01[i].y * kb2y;
      }
    }

    float inv[5];
#pragma unroll
    for (int i = 0; i < 5; ++i) {
      float s0x = acc[i][0].x * scale, s0y = acc[i][0].y * scale;
      float s1x = acc[i][1].x * scale, s1y = acc[i][1].y * scale;
      float s2x = acc[i][2].x * scale, s2y = acc[i][2].y * scale;
      if (t >= 11) { s2x = -1e30f; s2y = -1e30f; }   // m=128+2t >= 150
      float mx = fmaxf(fmaxf(fmaxf(s0x, s0y), fmaxf(s1x, s1y)), fmaxf(s2x, s2y));
#pragma unroll
      for (int off = 16; off > 0; off >>= 1) mx = fmaxf(mx, __shfl_xor(mx, off, 32));
      float p0x = __expf(s0x - mx), p0y = __expf(s0y - mx);
      float p1x = __expf(s1x - mx), p1y = __expf(s1y - mx);
      float p2x = __expf(s2x - mx), p2y = __expf(s2y - mx);
      float ss = p0x + p0y + p1x + p1y + p2x + p2y;
#pragma unroll
      for (int off = 16; off > 0; off >>= 1) ss += __shfl_xor(ss, off, 32);
      inv[i] = 1.f / ss;
      const int rw = rb_us + i * 152 + 2 * t;
      *(unsigned int*)&aru[rw]      = pkbf(p0x, p0y);
      *(unsigned int*)&aru[rw + 64] = pkbf(p1x, p1y);
      if (t <= 11) *(unsigned int*)&aru[rw + 128] = pkbf(p2x, p2y);  // t=11 -> zeros @150,151
    }

    float pv[5] = {0.f, 0.f, 0.f, 0.f, 0.f};
    const int vb = VB_US + t * 164;
    for (int mq = 0; mq < 38; ++mq) {
      uint2 vv = *(const uint2*)&aru[vb + 4 * mq];
#pragma unroll
      for (int i = 0; i < 5; ++i) {
        uint2 pp = *(const uint2*)&aru[rb_us + i * 152 + 4 * mq];
        pv[i] = bdot2(pp.x, vv.x, pv[i]);
        pv[i] = bdot2(pp.y, vv.y, pv[i]);
      }
    }
#pragma unroll
    for (int i = 0; i < 5; ++i) ms += pv[i] * inv[i];
  }
}

__global__ __launch_bounds__(256) void k_cattn(const float* __restrict__ red,
                                               const float* __restrict__ cw,
                                               const float* __restrict__ wq,
                                               const float* __restrict__ wk,
                                               const float* __restrict__ wv,
                                               const float* __restrict__ wo,
                                               float* __restrict__ cfa,
                                               float* __restrict__ cfs,
                                               float* __restrict__ eout,
                                               int wg) {
  __shared__ float ar[ARENA];
  unsigned short* aru = (unsigned short*)ar;
  const int s = blockIdx.x;
  const int tid = threadIdx.x;
  const int g = tid >> 5;
  const int t = tid & 31;

  float* a0g = cfa + (size_t)(2 * s) * (CC * LC);
  float* a1g = a0g + CC * LC;
  float* sgw = cfs + (size_t)s * (CC * LC);

  // ---- C1: stage comp weights + red pair (stride 156) ----
  for (int i = tid; i < CC * 3 * CC; i += 256) {
    int c = i & 31; int kk = i >> 5;
    ar[FWS + kk * 32 + c] = cw[c * (CC * 3) + kk];
  }
  if (tid < CC) {
    ar[FIN0 + tid * 156 + 0] = 0.f; ar[FIN0 + tid * 156 + 1] = 0.f;
    ar[FIN0 + tid * 156 + 152] = 0.f; ar[FIN0 + tid * 156 + 153] = 0.f;
    ar[FIN1 + tid * 156 + 0] = 0.f; ar[FIN1 + tid * 156 + 1] = 0.f;
    ar[FIN1 + tid * 156 + 152] = 0.f; ar[FIN1 + tid * 156 + 153] = 0.f;
  }
  {
    const float* s0 = red + (size_t)(2 * s) * (CC * LL);
    const float* s1 = s0 + CC * LL;
    for (int i = tid; i < CC * LL; i += 256) {
      int ic = i / LL; int l = i - ic * LL;
      ar[FIN0 + ic * 156 + l + 2] = s0[i];
      ar[FIN1 + ic * 156 + l + 2] = s1[i];
    }
  }
  __syncthreads();

  // ---- C2: compress conv into registers (pre-relu v0, v1) ----
  const int j0 = g * 10;
  const int nj = (LC - j0 < 10) ? (LC - j0) : 10;
  float v0[10], v1[10];
#pragma unroll
  for (int j = 0; j < 10; ++j) { v0[j] = 0.f; v1[j] = 0.f; }
  for (int ic = 0; ic < CC; ++ic) {
    float w0 = ar[FWS + (ic * 3 + 0) * 32 + t];
    float w1 = ar[FWS + (ic * 3 + 1) * 32 + t];
    float w2 = ar[FWS + (ic * 3 + 2) * 32 + t];
    float xa[12], xb[12];
#pragma unroll
    for (int i = 0; i < 12; ++i) {
      xa[i] = ar[FIN0 + ic * 156 + 2 * j0 + 2 * i];
      xb[i] = ar[FIN1 + ic * 156 + 2 * j0 + 2 * i];
    }
#pragma unroll
    for (int j = 0; j < 10; ++j) {
      v0[j] += w0 * xa[j] + w1 * xa[j + 1] + w2 * xa[j + 2];
      v1[j] += w0 * xb[j] + w1 * xb[j + 1] + w2 * xb[j + 2];
    }
  }
  __syncthreads();   // FIN/FWS reads done -> arena re-laid for attn

  // ---- C3: outputs -> arena (AKVt bf16, CF0 fp32) + globals + weights ----
  for (int j = 0; j < nj; ++j) {
    const int jj = j0 + j;
    float r0 = fmaxf(v0[j], 0.f);
    float r1 = fmaxf(v1[j], 0.f);
    float cs = fmaxf(v0[j] + v1[j], 0.f);
    aru[jj * 32 + t]        = f2bf(cs);        // AKVt rows 0..74  = cfs
    aru[(75 + jj) * 32 + t] = f2bf(r0 + r1);   // AKVt rows 75..149 = cfa0+cfa1
    ar[BCF + t * 77 + jj]   = r0;              // CF0 = cfa0 (fp32)
    a1g[t * 75 + jj] = r1;                     // cfa1 -> global (B1(1) readback)
    if (wg) {
      a0g[t * 75 + jj] = r0;                   // for k_meta
      sgw[t * 75 + jj] = cs;
    }
  }
  for (int i = tid; i < CC * CC; i += 256) {
    int o = i >> 5, ii = i & 31;
    ar[BWQ + ii * 33 + o] = wq[i];
    ar[BWK + ii * 33 + o] = wk[i];
    ar[BWV + ii * 33 + o] = wv[i];
  }
  __syncthreads();

  // ---- B1(0): q0 -> QT (fp32), cfsum0 from CF0 ----
  float cfp0 = 0.f;
  {
    float wqc[32];
#pragma unroll
    for (int ii = 0; ii < 32; ++ii) wqc[ii] = ar[BWQ + ii * 33 + t];
    for (int row = g; row < 75; row += 8) {
      float acc = 0.f;
#pragma unroll
      for (int ii = 0; ii < 32; ++ii) acc += wqc[ii] * ar[BCF + ii * 77 + row];
      ar[BQT + row * 32 + t] = acc;
      cfp0 += ar[BCF + t * 77 + row];
    }
  }
  __syncthreads();   // QT0 ready; CF0 reads done -> KBb may overwrite

  // ---- B2 (ONCE): k,v projections via bf16 dot2 -> KBb, VBb ----
  {
    unsigned int wk2[16], wv2[16];
    {
      float wkc[32], wvc[32];
#pragma unroll
      for (int ii = 0; ii < 32; ++ii) {
        wkc[ii] = ar[BWK + ii * 33 + t];
        wvc[ii] = ar[BWV + ii * 33 + t];
      }
#pragma unroll
      for (int j = 0; j < 16; ++j) {
        wk2[j] = pkbf(wkc[2 * j], wkc[2 * j + 1]);
        wv2[j] = pkbf(wvc[2 * j], wvc[2 * j + 1]);
      }
    }
    for (int idx = tid; idx < CC * LL; idx += 256) {
      int o = idx & 31, m = idx >> 5;   // o == t (stride-256 keeps low 5 bits)
      const unsigned int* kvrow = (const unsigned int*)&aru[m * 32];  // broadcast
      float ka = 0.f, va = 0.f;
#pragma unroll
      for (int j = 0; j < 16; ++j) {
        unsigned int u = kvrow[j];
        ka = bdot2(wk2[j], u, ka);
        va = bdot2(wv2[j], u, va);
      }
      aru[KB_US + o * 154 + m] = f2bf(ka);
      aru[VB_US + o * 164 + m] = f2bf(va);
    }
    if (tid < 32) *(unsigned int*)&aru[VB_US + tid * 164 + 150] = 0u;  // PV pad
  }
  __syncthreads();   // KBb/VBb ready; AKVt+WK+WV dead -> ROWPb/PART free

  // ---- D(0): allele0 ----
  float ms0 = 0.f;
  attn_phase_d(ar, g, t, ms0);
  __syncthreads();   // D(0) QT reads done -> B1(1) may rewrite QT

  // ---- B1(1): q1 -> QT from GLOBAL cfa1 (L2-hot), cfsum1 ----
  float cfp1 = 0.f;
  {
    float wqc[32];
#pragma unroll
    for (int ii = 0; ii < 32; ++ii) wqc[ii] = ar[BWQ + ii * 33 + t];
    for (int row = g; row < 75; row += 8) {
      float acc = 0.f;
#pragma unroll
      for (int ii = 0; ii < 32; ++ii) acc += wqc[ii] * a1g[ii * 75 + row];  // broadcast
      ar[BQT + row * 32 + t] = acc;
      cfp1 += a1g[t * 75 + row];
    }
  }
  __syncthreads();   // QT1 ready

  // ---- D(1): allele1 ----
  float ms1 = 0.f;
  attn_phase_d(ar, g, t, ms1);

  ar[BPART + g * 32 + t]       = cfp0 + ms0;
  ar[BPART + 256 + g * 32 + t] = cfp1 + ms1;
  __syncthreads();

  // ---- epilogue: mean over l, project with wo (both alleles) ----
  if (tid < 64) {
    int al = tid >> 5, tt = tid & 31;
    float tot = 0.f;
#pragma unroll
    for (int gg = 0; gg < 8; ++gg) tot += ar[BPART + al * 256 + gg * 32 + tt];
    ar[BMS + al * 32 + tt] = tot * (1.f / 75.f);
  }
  __syncthreads();
  if (tid < 4) {
    int al = tid >> 1, o2 = tid & 1;
    float e = 0.f;
#pragma unroll
    for (int c2 = 0; c2 < CC; ++c2) e += wo[o2 * CC + c2] * ar[BMS + al * 32 + c2];
    eout[s * 4 + tid] = e;   // = eout[(2s+al)*2 + o2]
  }
}

// ---------------------------------------------------------------------------
// K5: meta head per site (unchanged)
// ---------------------------------------------------------------------------
__global__ __launch_bounds__(64) void k_meta(const float* __restrict__ cfs0,
                                             const float* __restrict__ cfa2,
                                             const float* __restrict__ mw,
                                             const float* __restrict__ mb,
                                             float* __restrict__ mout) {
  __shared__ float feat[64];
  __shared__ float lgt[3];
  const int s = blockIdx.x;
  const int tid = threadIdx.x;
  float f = 0.f;
  if (tid < 32) {
    const float* p = cfs0 + (size_t)s * (CC * LC) + tid * LC;
    for (int l = 0; l < LC; ++l) f += p[l];
  } else {
    const float* p0 = cfa2 + (size_t)(2 * s) * (CC * LC) + (tid - 32) * LC;
    const float* p1 = cfa2 + (size_t)(2 * s + 1) * (CC * LC) + (tid - 32) * LC;
    for (int l = 0; l < LC; ++l) f += p0[l] + p1[l];
  }
  feat[tid] = f * (1.f / 75.f);
  __syncthreads();
  if (tid < 3) {
    float acc2 = mb[tid];
    for (int c2 = 0; c2 < 64; ++c2) acc2 += mw[tid * 64 + c2] * feat[c2];
    lgt[tid] = acc2;
  }
  __syncthreads();
  if (tid < 3) {
    float mx = fmaxf(lgt[0], fmaxf(lgt[1], lgt[2]));
    float e0 = __expf(lgt[0] - mx), e1 = __expf(lgt[1] - mx), e2 = __expf(lgt[2] - mx);
    mout[s * 3 + tid] = __expf(lgt[tid] - mx) / (e0 + e1 + e2);
  }
}

// ---------------------------------------------------------------------------
extern "C" void kernel_launch(void* const* d_in, const int* in_sizes, int n_in,
                              void* d_out, int out_size, void* d_ws, size_t ws_size,
                              hipStream_t stream) {
  const float* t0      = (const float*)d_in[0];
  const float* t1      = (const float*)d_in[1];
  const float* conv0_w = (const float*)d_in[2];
  const float* conv1_w = (const float*)d_in[3];
  const float* comp0_w = (const float*)d_in[4];
  const float* comp1_w = (const float*)d_in[5];
  const float* comp2_w = (const float*)d_in[6];
  const float* xq0 = (const float*)d_in[7];
  const float* xk0 = (const float*)d_in[8];
  const float* xv0 = (const float*)d_in[9];
  const float* xo0 = (const float*)d_in[10];
  const float* xq1 = (const float*)d_in[11];
  const float* xk1 = (const float*)d_in[12];
  const float* xv1 = (const float*)d_in[13];
  const float* xo1 = (const float*)d_in[14];
  const float* xq2 = (const float*)d_in[15];
  const float* xk2 = (const float*)d_in[16];
  const float* xv2 = (const float*)d_in[17];
  const float* xo2 = (const float*)d_in[18];
  const float* comb_w = (const float*)d_in[19];
  const float* meta_w = (const float*)d_in[20];
  const float* meta_b = (const float*)d_in[21];

  float* wsf  = (float*)d_ws;
  float* red0 = wsf;
  float* red1 = red0 + (size_t)NA * CC * LL;
  float* cfa  = red1 + (size_t)NA * CC * LL;
  float* cfs0 = cfa + (size_t)NA * CC * LC;
  float* out  = (float*)d_out;

  k_conv_sum_mfma<<<NA, 256, 0, stream>>>(t0, conv0_w, red0);
  k_conv_sum_mfma<<<NA, 256, 0, stream>>>(t1, conv1_w, red1);

  k_cattn<<<NS, 256, 0, stream>>>(red0, comp0_w, xq0, xk0, xv0, xo0,
                                  cfa, cfs0, out + 0, 0);
  k_cattn<<<NS, 256, 0, stream>>>(red1, comp1_w, xq1, xk1, xv1, xo1,
                                  cfa, cfs0, out + 2 * NA, 0);

  k_comb<<<NA, 256, 0, stream>>>(red0, red1, comb_w, red0);
  k_cattn<<<NS, 256, 0, stream>>>(red0, comp2_w, xq2, xk2, xv2, xo2,
                                  cfa, cfs0, out + 4 * NA, 1);

  k_meta<<<NS, 64, 0, stream>>>(cfs0, cfa, meta_w, meta_b, out + 6 * NA);
}

// Round 16
// 1203.837 us; speedup vs baseline: 1.5200x; 1.0228x over previous
//
#include <hip/hip_runtime.h>
#include <math.h>

#define NS 1024
#define NA 2048
#define CIN 16
#define CC 32
#define LL 150
#define LC 75

typedef __attribute__((ext_vector_type(8))) short short8;
typedef __attribute__((ext_vector_type(4))) float float4v;

__device__ __forceinline__ unsigned short f2bf(float f) {
  // round-to-nearest-even fp32 -> bf16
  unsigned int u = __float_as_uint(f);
  unsigned int r = (u + 0x7FFFu + ((u >> 16) & 1u)) >> 16;
  return (unsigned short)r;
}

__device__ __forceinline__ unsigned int pkbf(float lo, float hi) {
  return (unsigned int)f2bf(lo) | ((unsigned int)f2bf(hi) << 16);
}

__device__ __forceinline__ float bflo(unsigned int u) { return __uint_as_float(u << 16); }
__device__ __forceinline__ float bfhi(unsigned int u) { return __uint_as_float(u & 0xffff0000u); }

// 2x bf16 MAC with f32 accumulate. HW v_dot2_f32_bf16 when available.
#if __has_builtin(__builtin_amdgcn_fdot2_f32_bf16)
typedef __attribute__((ext_vector_type(2))) __bf16 bf16x2;
__device__ __forceinline__ float bdot2(unsigned int a, unsigned int b, float c) {
  return __builtin_amdgcn_fdot2_f32_bf16(__builtin_bit_cast(bf16x2, a),
                                         __builtin_bit_cast(bf16x2, b), c, false);
}
#else
__device__ __forceinline__ float bdot2(unsigned int a, unsigned int b, float c) {
  return c + bflo(a) * bflo(b) + bfhi(a) * bfhi(b);
}
#endif

// ---------------------------------------------------------------------------
// K1 v7: conv1d(k=5,pad=2) + ReLU + sum over 16 reads (unchanged from R11).
// ---------------------------------------------------------------------------
__global__ __launch_bounds__(256) void k_conv_sum_mfma(const float* __restrict__ x,
                                                       const float* __restrict__ w,
                                                       float* __restrict__ red) {
  __shared__ unsigned short xs[2][154 * 32];   // 2 x 616 slots of 16B
  const int a = blockIdx.x;
  const int tid = threadIdx.x;
  const int lane = tid & 63;
  const int wv = tid >> 6;

  short8 afr[2][3];
  {
    const int mrow = lane & 15;
    const int h = lane >> 4;
    for (int mt = 0; mt < 2; ++mt) {
      const int c = mt * 16 + mrow;
      for (int s = 0; s < 3; ++s) {
        short8 f;
#pragma unroll
        for (int j = 0; j < 8; ++j) {
          int ic = 4 * h + (j >> 1);
          int tap = 2 * s + (j & 1);
          float wval = (tap < 5) ? w[c * 80 + ic * 5 + tap] : 0.f;
          f[j] = (short)f2bf(wval);
        }
        afr[mt][s] = f;
      }
    }
  }

  float4v sum[2][3];
#pragma unroll
  for (int mt = 0; mt < 2; ++mt)
#pragma unroll
    for (int nt = 0; nt < 3; ++nt) sum[mt][nt] = (float4v)(0.f);

  const int nbase = wv * 48;
  const int nrow = lane & 15;
  const int hh = lane >> 4;
  const float4v zf = (float4v)(0.f);

  auto stage = [&](int r, int buf) {
    const float* xr = x + (size_t)(a * 16 + r) * (CIN * LL);
    unsigned int* xb32 = (unsigned int*)xs[buf];
    for (int idx = tid; idx < 16 * 38; idx += 256) {
      const int ic = idx & 15;
      const int seg = idx >> 4;
      const int l0 = seg * 4;
      const float* row = xr + ic * LL;
      float v0, v1, v2, v3, v4;
      if (seg < 37) {
        float2 u = *(const float2*)(row + l0);
        float2 u2 = *(const float2*)(row + l0 + 2);
        v0 = u.x; v1 = u.y; v2 = u2.x; v3 = u2.y;
        v4 = row[l0 + 4];
      } else {
        float2 u = *(const float2*)(row + 148);
        v0 = u.x; v1 = u.y; v2 = 0.f; v3 = 0.f; v4 = 0.f;
      }
      const int hb = 4 * (ic >> 2) + (ic & 3);
      unsigned int* b32 = xb32 + 16 * (l0 + 2) + hb;
      b32[0]  = pkbf(v0, v1);
      b32[16] = pkbf(v1, v2);
      b32[32] = pkbf(v2, v3);
      b32[48] = pkbf(v3, v4);
    }
    if (tid < 32) {
      const int ic = tid & 15;
      const int which = tid >> 4;
      const int hb = 4 * (ic >> 2) + (ic & 3);
      xb32[16 * which + hb] = which ? pkbf(0.f, xr[ic * LL]) : 0u;
    }
  };

  stage(0, 0);
  __syncthreads();

  for (int r = 0; r < 16; ++r) {
    const int cur = r & 1;
    if (r + 1 < 16) stage(r + 1, cur ^ 1);

    float4v acc[2][3];
#pragma unroll
    for (int s = 0; s < 3; ++s) {
#pragma unroll
      for (int nt = 0; nt < 3; ++nt) {
        int p = nbase + nt * 16 + nrow + 2 * s;
        if (p >= 154) p -= 154;
        short8 bfrag = *(const short8*)&xs[cur][(4 * p + hh) * 8];
#pragma unroll
        for (int mt = 0; mt < 2; ++mt) {
          acc[mt][nt] = __builtin_amdgcn_mfma_f32_16x16x32_bf16(
              afr[mt][s], bfrag, (s == 0) ? zf : acc[mt][nt], 0, 0, 0);
        }
      }
    }
#pragma unroll
    for (int mt = 0; mt < 2; ++mt)
#pragma unroll
      for (int nt = 0; nt < 3; ++nt)
#pragma unroll
        for (int q = 0; q < 4; ++q) sum[mt][nt][q] += fmaxf(acc[mt][nt][q], 0.f);

    __syncthreads();
  }

  const int ccol = lane & 15;
  const int crow4 = (lane >> 4) * 4;
  for (int mt = 0; mt < 2; ++mt)
    for (int nt = 0; nt < 3; ++nt) {
      int l = nbase + nt * 16 + ccol;
      if (l < LL) {
#pragma unroll
        for (int q = 0; q < 4; ++q) {
          int c = mt * 16 + crow4 + q;
          red[(size_t)a * (CC * LL) + c * LL + l] = sum[mt][nt][q];
        }
      }
    }
}

// ---------------------------------------------------------------------------
// K2: red2 = relu(comb_w @ [red0|red1]) in place over red0 (unchanged)
// ---------------------------------------------------------------------------
__global__ __launch_bounds__(256) void k_comb(const float* __restrict__ red0,
                                              const float* __restrict__ red1,
                                              const float* __restrict__ cw,
                                              float* __restrict__ out) {
  __shared__ float ins[64][152];
  __shared__ float cwl[64][CC];
  const int a = blockIdx.x;
  const int tid = threadIdx.x;

  for (int i = tid; i < 64 * CC; i += 256) {
    int c = i & 31; int c2 = i >> 5;
    cwl[c2][c] = cw[c * 64 + c2];
  }
  for (int i = tid; i < CC * LL; i += 256) {
    int c2 = i / LL; int l = i - c2 * LL;
    ins[c2][l] = red0[(size_t)a * (CC * LL) + i];
    ins[32 + c2][l] = red1[(size_t)a * (CC * LL) + i];
  }
  __syncthreads();

  const int c = tid & 31;
  const int lg = tid >> 5;
  const int l0 = lg * 19;
  const int nl = (LL - l0 < 19) ? (LL - l0) : 19;
  float v[19];
#pragma unroll
  for (int j = 0; j < 19; ++j) v[j] = 0.f;
  for (int c2 = 0; c2 < 64; ++c2) {
    float wv = cwl[c2][c];
#pragma unroll
    for (int j = 0; j < 19; ++j) v[j] += wv * ins[c2][l0 + j];
  }
  float* o = out + (size_t)a * (CC * LL) + c * LL + l0;
  for (int j = 0; j < nl; ++j) o[j] = fmaxf(v[j], 0.f);
}

// ---------------------------------------------------------------------------
// K4 v10 "k_cattn": fused per-site compressor + cross-attention, all-bf16 LDS.
// v9's failure was a sizing bug: [75][32]us planes are 1200 fl (not 600) ->
// QTb overlapped CF0t and clobbered it. v10 keeps the v9 design with correct
// geometry + aliasing:
//  - weight packs (wq2/wk2/wv2) hoisted before B1(0) (+1 barrier), so
//    QTb can alias dead WK+WV-head;
//  - ROWPb split: groups 0-5 over dead AKVt, groups 6-7 over dead WQ;
//  - PART/MS in dead WV tail.
// Arena = 13056 fl (52224 B) -> 3 blocks/CU (same as passing v8).
//
// Float-offset map (fl = floats, us = ushorts):
//  AKVt  bf16 [150][32]us @us 0      = fl 0..2399      (dead after B2)
//  WK  @fl 2400..3455  WV @3456..4511  WQ @4512..5567  (dead after packs)
//  QTb   bf16 [75][32]us @us 4800    = fl 2400..3599   (over WK+WV head)
//  PART  @fl 3600..4111, MS @4112..4175 (WV tail; written end of D(1))
//  ROWPb groups 0-5 @us g*760 (fl 0..2279), 6-7 @us 9024+(g-6)*760
//        (fl 4512..5271, over dead WQ)
//  CF0t  bf16 [75][32]us @us 11136   = fl 5568..6767
//  CF1t  bf16 [75][32]us @us 13536   = fl 6768..7967
//  KBb   bf16 [32][154]us @us 15936  = fl 7968..10431
//  VBb   bf16 [32][164]us @us 20864  = fl 10432..13055
// Compress phase aliases (dead before C3): FIN0@0 [32][154], FIN1@4928,
//  FWS@9856 [96][32] (end 12928).
// ---------------------------------------------------------------------------
#define AKV_US 0
#define BWK    2400
#define BWV    3456
#define BWQ    4512
#define QT_US  4800
#define BPART  3600
#define BMS    4112
#define CF0_US 11136
#define CF1_US 13536
#define KB_US  15936
#define VB_US  20864
#define ARENA  13056
#define FIN0   0
#define FIN1   4928
#define FWS    9856

__device__ __forceinline__ void attn_phase_d(float* __restrict__ ar, int g, int t,
                                             float& ms) {
  unsigned short* aru = (unsigned short*)ar;
  const float scale = 0.17677669529663687f;   // 1/sqrt(32)
  const int rb_us = (g < 6) ? g * 760 : 9024 + (g - 6) * 760;  // ROWPb base
#pragma unroll 1
  for (int cc = 0; cc < 2; ++cc) {
    const int ch = g + 8 * cc;
    if (ch >= 15) break;
    const int r0 = ch * 5;

    float2 acc[5][3];
#pragma unroll
    for (int i = 0; i < 5; ++i)
#pragma unroll
      for (int u = 0; u < 3; ++u) acc[i][u] = make_float2(0.f, 0.f);

#pragma unroll 1
    for (int c2 = 0; c2 < 32; c2 += 2) {
      float2 q01[5];
#pragma unroll
      for (int i = 0; i < 5; ++i) {
        unsigned int qp = *(const unsigned int*)&aru[QT_US + (r0 + i) * 32 + c2];
        q01[i] = make_float2(bflo(qp), bfhi(qp));   // channels c2, c2+1
      }
      const int k0 = KB_US + c2 * 154 + 2 * t;
      const int k1 = k0 + 154;
      unsigned int a0 = *(const unsigned int*)&aru[k0];
      unsigned int a1 = *(const unsigned int*)&aru[k0 + 64];
      unsigned int a2 = *(const unsigned int*)&aru[k0 + 128];
      unsigned int b0 = *(const unsigned int*)&aru[k1];
      unsigned int b1 = *(const unsigned int*)&aru[k1 + 64];
      unsigned int b2 = *(const unsigned int*)&aru[k1 + 128];
      float ka0x = bflo(a0), ka0y = bfhi(a0);
      float ka1x = bflo(a1), ka1y = bfhi(a1);
      float ka2x = bflo(a2), ka2y = bfhi(a2);
      float kb0x = bflo(b0), kb0y = bfhi(b0);
      float kb1x = bflo(b1), kb1y = bfhi(b1);
      float kb2x = bflo(b2), kb2y = bfhi(b2);
#pragma unroll
      for (int i = 0; i < 5; ++i) {
        acc[i][0].x += q01[i].x * ka0x + q01[i].y * kb0x;
        acc[i][0].y += q01[i].x * ka0y + q01[i].y * kb0y;
        acc[i][1].x += q01[i].x * ka1x + q01[i].y * kb1x;
        acc[i][1].y += q01[i].x * ka1y + q01[i].y * kb1y;
        acc[i][2].x += q01[i].x * ka2x + q01[i].y * kb2x;
        acc[i][2].y += q01[i].x * ka2y + q01[i].y * kb2y;
      }
    }

    float inv[5];
#pragma unroll
    for (int i = 0; i < 5; ++i) {
      float s0x = acc[i][0].x * scale, s0y = acc[i][0].y * scale;
      float s1x = acc[i][1].x * scale, s1y = acc[i][1].y * scale;
      float s2x = acc[i][2].x * scale, s2y = acc[i][2].y * scale;
      if (t >= 11) { s2x = -1e30f; s2y = -1e30f; }   // m=128+2t >= 150
      float mx = fmaxf(fmaxf(fmaxf(s0x, s0y), fmaxf(s1x, s1y)), fmaxf(s2x, s2y));
#pragma unroll
      for (int off = 16; off > 0; off >>= 1) mx = fmaxf(mx, __shfl_xor(mx, off, 32));
      float p0x = __expf(s0x - mx), p0y = __expf(s0y - mx);
      float p1x = __expf(s1x - mx), p1y = __expf(s1y - mx);
      float p2x = __expf(s2x - mx), p2y = __expf(s2y - mx);
      float ss = p0x + p0y + p1x + p1y + p2x + p2y;
#pragma unroll
      for (int off = 16; off > 0; off >>= 1) ss += __shfl_xor(ss, off, 32);
      inv[i] = 1.f / ss;
      const int rw = rb_us + i * 152 + 2 * t;
      *(unsigned int*)&aru[rw]      = pkbf(p0x, p0y);
      *(unsigned int*)&aru[rw + 64] = pkbf(p1x, p1y);
      if (t <= 11) *(unsigned int*)&aru[rw + 128] = pkbf(p2x, p2y);  // t=11 -> zeros @150,151
    }

    float pv[5] = {0.f, 0.f, 0.f, 0.f, 0.f};
    const int vb = VB_US + t * 164;
    for (int mq = 0; mq < 38; ++mq) {
      uint2 vv = *(const uint2*)&aru[vb + 4 * mq];
#pragma unroll
      for (int i = 0; i < 5; ++i) {
        uint2 pp = *(const uint2*)&aru[rb_us + i * 152 + 4 * mq];
        pv[i] = bdot2(pp.x, vv.x, pv[i]);
        pv[i] = bdot2(pp.y, vv.y, pv[i]);
      }
    }
#pragma unroll
    for (int i = 0; i < 5; ++i) ms += pv[i] * inv[i];
  }
}

__global__ __launch_bounds__(256) void k_cattn(const float* __restrict__ red,
                                               const float* __restrict__ cw,
                                               const float* __restrict__ wq,
                                               const float* __restrict__ wk,
                                               const float* __restrict__ wv,
                                               const float* __restrict__ wo,
                                               float* __restrict__ cfa,
                                               float* __restrict__ cfs,
                                               float* __restrict__ eout,
                                               int wg) {
  __shared__ float ar[ARENA];
  unsigned short* aru = (unsigned short*)ar;
  const int s = blockIdx.x;
  const int tid = threadIdx.x;
  const int g = tid >> 5;
  const int t = tid & 31;

  float* a0g = cfa + (size_t)(2 * s) * (CC * LC);
  float* a1g = a0g + CC * LC;
  float* sgw = cfs + (size_t)s * (CC * LC);

  // ---- C1: stage comp weights + red pair (stride 154) ----
  for (int i = tid; i < CC * 3 * CC; i += 256) {
    int c = i & 31; int kk = i >> 5;
    ar[FWS + kk * 32 + c] = cw[c * (CC * 3) + kk];
  }
  if (tid < CC) {
    ar[FIN0 + tid * 154 + 0] = 0.f; ar[FIN0 + tid * 154 + 1] = 0.f;
    ar[FIN0 + tid * 154 + 152] = 0.f; ar[FIN0 + tid * 154 + 153] = 0.f;
    ar[FIN1 + tid * 154 + 0] = 0.f; ar[FIN1 + tid * 154 + 1] = 0.f;
    ar[FIN1 + tid * 154 + 152] = 0.f; ar[FIN1 + tid * 154 + 153] = 0.f;
  }
  {
    const float* s0 = red + (size_t)(2 * s) * (CC * LL);
    const float* s1 = s0 + CC * LL;
    for (int i = tid; i < CC * LL; i += 256) {
      int ic = i / LL; int l = i - ic * LL;
      ar[FIN0 + ic * 154 + l + 2] = s0[i];
      ar[FIN1 + ic * 154 + l + 2] = s1[i];
    }
  }
  __syncthreads();

  // ---- C2: compress conv into registers (pre-relu v0, v1) ----
  const int j0 = g * 10;
  const int nj = (LC - j0 < 10) ? (LC - j0) : 10;
  float v0[10], v1[10];
#pragma unroll
  for (int j = 0; j < 10; ++j) { v0[j] = 0.f; v1[j] = 0.f; }
  for (int ic = 0; ic < CC; ++ic) {
    float w0 = ar[FWS + (ic * 3 + 0) * 32 + t];
    float w1 = ar[FWS + (ic * 3 + 1) * 32 + t];
    float w2 = ar[FWS + (ic * 3 + 2) * 32 + t];
    float xa[12], xb[12];
#pragma unroll
    for (int i = 0; i < 12; ++i) {
      // reads beyond index 153 land in the next region; values only feed
      // v[j] with j >= nj which are never stored -> harmless.
      xa[i] = ar[FIN0 + ic * 154 + 2 * j0 + 2 * i];
      xb[i] = ar[FIN1 + ic * 154 + 2 * j0 + 2 * i];
    }
#pragma unroll
    for (int j = 0; j < 10; ++j) {
      v0[j] += w0 * xa[j] + w1 * xa[j + 1] + w2 * xa[j + 2];
      v1[j] += w0 * xb[j] + w1 * xb[j + 1] + w2 * xb[j + 2];
    }
  }
  __syncthreads();   // FIN/FWS reads done -> arena re-laid for attn

  // ---- C3: outputs -> arena (AKVt/CF0t/CF1t bf16) + globals + weights ----
  for (int j = 0; j < nj; ++j) {
    const int jj = j0 + j;
    float r0 = fmaxf(v0[j], 0.f);
    float r1 = fmaxf(v1[j], 0.f);
    float cs = fmaxf(v0[j] + v1[j], 0.f);
    aru[AKV_US + jj * 32 + t]        = f2bf(cs);        // AKVt rows 0..74  = cfs
    aru[AKV_US + (75 + jj) * 32 + t] = f2bf(r0 + r1);   // rows 75..149 = cfa0+cfa1
    aru[CF0_US + jj * 32 + t]        = f2bf(r0);
    aru[CF1_US + jj * 32 + t]        = f2bf(r1);
    if (wg) {                      // only the k_meta stream needs globals
      a0g[t * 75 + jj] = r0;
      a1g[t * 75 + jj] = r1;
      sgw[t * 75 + jj] = cs;
    }
  }
  for (int i = tid; i < CC * CC; i += 256) {
    int o = i >> 5, ii = i & 31;
    ar[BWQ + ii * 33 + o] = wq[i];
    ar[BWK + ii * 33 + o] = wk[i];
    ar[BWV + ii * 33 + o] = wv[i];
  }
  __syncthreads();

  // ---- packs: wq2/wk2/wv2 -> registers (weight LDS dead afterwards) ----
  unsigned int wq2[16], wk2[16], wv2[16];
  {
    float wqc[32], wkc[32], wvc[32];
#pragma unroll
    for (int ii = 0; ii < 32; ++ii) {
      wqc[ii] = ar[BWQ + ii * 33 + t];
      wkc[ii] = ar[BWK + ii * 33 + t];
      wvc[ii] = ar[BWV + ii * 33 + t];
    }
#pragma unroll
    for (int j = 0; j < 16; ++j) {
      wq2[j] = pkbf(wqc[2 * j], wqc[2 * j + 1]);
      wk2[j] = pkbf(wkc[2 * j], wkc[2 * j + 1]);
      wv2[j] = pkbf(wvc[2 * j], wvc[2 * j + 1]);
    }
  }
  __syncthreads();   // all packs done -> QTb may overwrite WK/WV-head

  // ---- B1(0): q0 -> QTb (over dead WK/WV-head), cfsum0 from CF0t ----
  float cfp0 = 0.f;
  for (int row = g; row < 75; row += 8) {
    const unsigned int* cr = (const unsigned int*)&aru[CF0_US + row * 32];
    float acc = 0.f;
#pragma unroll
    for (int j = 0; j < 16; ++j) acc = bdot2(wq2[j], cr[j], acc);
    aru[QT_US + row * 32 + t] = f2bf(acc);
    cfp0 += bflo((unsigned int)aru[CF0_US + row * 32 + t]);
  }
  __syncthreads();   // QTb(0) ready

  // ---- B2 (ONCE): k,v projections via bf16 dot2 -> KBb, VBb ----
  {
    for (int idx = tid; idx < CC * LL; idx += 256) {
      int o = idx & 31, m = idx >> 5;   // o == t (stride-256 keeps low 5 bits)
      const unsigned int* kvrow = (const unsigned int*)&aru[AKV_US + m * 32];
      float ka = 0.f, va = 0.f;
#pragma unroll
      for (int j = 0; j < 16; ++j) {
        unsigned int u = kvrow[j];
        ka = bdot2(wk2[j], u, ka);
        va = bdot2(wv2[j], u, va);
      }
      aru[KB_US + o * 154 + m] = f2bf(ka);
      aru[VB_US + o * 164 + m] = f2bf(va);
    }
    if (tid < 32) *(unsigned int*)&aru[VB_US + tid * 164 + 150] = 0u;  // PV pad
  }
  __syncthreads();   // KBb/VBb ready; AKVt + WQ dead -> ROWPb regions free

  // ---- D(0): allele0 ----
  float ms0 = 0.f;
  attn_phase_d(ar, g, t, ms0);
  __syncthreads();   // D(0) QTb reads done -> B1(1) may rewrite QTb

  // ---- B1(1): q1 -> QTb from CF1t (LDS — no global round-trip) ----
  float cfp1 = 0.f;
  for (int row = g; row < 75; row += 8) {
    const unsigned int* cr = (const unsigned int*)&aru[CF1_US + row * 32];
    float acc = 0.f;
#pragma unroll
    for (int j = 0; j < 16; ++j) acc = bdot2(wq2[j], cr[j], acc);
    aru[QT_US + row * 32 + t] = f2bf(acc);
    cfp1 += bflo((unsigned int)aru[CF1_US + row * 32 + t]);
  }
  __syncthreads();   // QTb(1) ready

  // ---- D(1): allele1 ----
  float ms1 = 0.f;
  attn_phase_d(ar, g, t, ms1);
  __syncthreads();   // D(1) done -> PART region (dead WV tail) safe to write

  ar[BPART + g * 32 + t]       = cfp0 + ms0;
  ar[BPART + 256 + g * 32 + t] = cfp1 + ms1;
  __syncthreads();

  // ---- epilogue: mean over l, project with wo (both alleles) ----
  if (tid < 64) {
    int al = tid >> 5, tt = tid & 31;
    float tot = 0.f;
#pragma unroll
    for (int gg = 0; gg < 8; ++gg) tot += ar[BPART + al * 256 + gg * 32 + tt];
    ar[BMS + al * 32 + tt] = tot * (1.f / 75.f);
  }
  __syncthreads();
  if (tid < 4) {
    int al = tid >> 1, o2 = tid & 1;
    float e = 0.f;
#pragma unroll
    for (int c2 = 0; c2 < CC; ++c2) e += wo[o2 * CC + c2] * ar[BMS + al * 32 + c2];
    eout[s * 4 + tid] = e;   // = eout[(2s+al)*2 + o2]
  }
}

// ---------------------------------------------------------------------------
// K5: meta head per site (unchanged)
// ---------------------------------------------------------------------------
__global__ __launch_bounds__(64) void k_meta(const float* __restrict__ cfs0,
                                             const float* __restrict__ cfa2,
                                             const float* __restrict__ mw,
                                             const float* __restrict__ mb,
                                             float* __restrict__ mout) {
  __shared__ float feat[64];
  __shared__ float lgt[3];
  const int s = blockIdx.x;
  const int tid = threadIdx.x;
  float f = 0.f;
  if (tid < 32) {
    const float* p = cfs0 + (size_t)s * (CC * LC) + tid * LC;
    for (int l = 0; l < LC; ++l) f += p[l];
  } else {
    const float* p0 = cfa2 + (size_t)(2 * s) * (CC * LC) + (tid - 32) * LC;
    const float* p1 = cfa2 + (size_t)(2 * s + 1) * (CC * LC) + (tid - 32) * LC;
    for (int l = 0; l < LC; ++l) f += p0[l] + p1[l];
  }
  feat[tid] = f * (1.f / 75.f);
  __syncthreads();
  if (tid < 3) {
    float acc2 = mb[tid];
    for (int c2 = 0; c2 < 64; ++c2) acc2 += mw[tid * 64 + c2] * feat[c2];
    lgt[tid] = acc2;
  }
  __syncthreads();
  if (tid < 3) {
    float mx = fmaxf(lgt[0], fmaxf(lgt[1], lgt[2]));
    float e0 = __expf(lgt[0] - mx), e1 = __expf(lgt[1] - mx), e2 = __expf(lgt[2] - mx);
    mout[s * 3 + tid] = __expf(lgt[tid] - mx) / (e0 + e1 + e2);
  }
}

// ---------------------------------------------------------------------------
extern "C" void kernel_launch(void* const* d_in, const int* in_sizes, int n_in,
                              void* d_out, int out_size, void* d_ws, size_t ws_size,
                              hipStream_t stream) {
  const float* t0      = (const float*)d_in[0];
  const float* t1      = (const float*)d_in[1];
  const float* conv0_w = (const float*)d_in[2];
  const float* conv1_w = (const float*)d_in[3];
  const float* comp0_w = (const float*)d_in[4];
  const float* comp1_w = (const float*)d_in[5];
  const float* comp2_w = (const float*)d_in[6];
  const float* xq0 = (const float*)d_in[7];
  const float* xk0 = (const float*)d_in[8];
  const float* xv0 = (const float*)d_in[9];
  const float* xo0 = (const float*)d_in[10];
  const float* xq1 = (const float*)d_in[11];
  const float* xk1 = (const float*)d_in[12];
  const float* xv1 = (const float*)d_in[13];
  const float* xo1 = (const float*)d_in[14];
  const float* xq2 = (const float*)d_in[15];
  const float* xk2 = (const float*)d_in[16];
  const float* xv2 = (const float*)d_in[17];
  const float* xo2 = (const float*)d_in[18];
  const float* comb_w = (const float*)d_in[19];
  const float* meta_w = (const float*)d_in[20];
  const float* meta_b = (const float*)d_in[21];

  float* wsf  = (float*)d_ws;
  float* red0 = wsf;
  float* red1 = red0 + (size_t)NA * CC * LL;
  float* cfa  = red1 + (size_t)NA * CC * LL;
  float* cfs0 = cfa + (size_t)NA * CC * LC;
  float* out  = (float*)d_out;

  k_conv_sum_mfma<<<NA, 256, 0, stream>>>(t0, conv0_w, red0);
  k_conv_sum_mfma<<<NA, 256, 0, stream>>>(t1, conv1_w, red1);

  k_cattn<<<NS, 256, 0, stream>>>(red0, comp0_w, xq0, xk0, xv0, xo0,
                                  cfa, cfs0, out + 0, 0);
  k_cattn<<<NS, 256, 0, stream>>>(red1, comp1_w, xq1, xk1, xv1, xo1,
                                  cfa, cfs0, out + 2 * NA, 0);

  k_comb<<<NA, 256, 0, stream>>>(red0, red1, comb_w, red0);
  k_cattn<<<NS, 256, 0, stream>>>(red0, comp2_w, xq2, xk2, xv2, xo2,
                                  cfa, cfs0, out + 4 * NA, 1);

  k_meta<<<NS, 64, 0, stream>>>(cfs0, cfa, meta_w, meta_b, out + 6 * NA);
}

// Round 17
// 1202.833 us; speedup vs baseline: 1.5212x; 1.0008x over previous
//
#include <hip/hip_runtime.h>
#include <math.h>

#define NS 1024
#define NA 2048
#define CIN 16
#define CC 32
#define LL 150
#define LC 75

typedef __attribute__((ext_vector_type(8))) short short8;
typedef __attribute__((ext_vector_type(4))) float float4v;

__device__ __forceinline__ unsigned short f2bf(float f) {
  // round-to-nearest-even fp32 -> bf16
  unsigned int u = __float_as_uint(f);
  unsigned int r = (u + 0x7FFFu + ((u >> 16) & 1u)) >> 16;
  return (unsigned short)r;
}

__device__ __forceinline__ unsigned int pkbf(float lo, float hi) {
  return (unsigned int)f2bf(lo) | ((unsigned int)f2bf(hi) << 16);
}

__device__ __forceinline__ float bflo(unsigned int u) { return __uint_as_float(u << 16); }
__device__ __forceinline__ float bfhi(unsigned int u) { return __uint_as_float(u & 0xffff0000u); }

// 2x bf16 MAC with f32 accumulate. HW v_dot2_f32_bf16 when available.
#if __has_builtin(__builtin_amdgcn_fdot2_f32_bf16)
typedef __attribute__((ext_vector_type(2))) __bf16 bf16x2;
__device__ __forceinline__ float bdot2(unsigned int a, unsigned int b, float c) {
  return __builtin_amdgcn_fdot2_f32_bf16(__builtin_bit_cast(bf16x2, a),
                                         __builtin_bit_cast(bf16x2, b), c, false);
}
#else
__device__ __forceinline__ float bdot2(unsigned int a, unsigned int b, float c) {
  return c + bflo(a) * bflo(b) + bfhi(a) * bfhi(b);
}
#endif

// ---------------------------------------------------------------------------
// K1 v8: conv1d(k=5,pad=2) + ReLU + sum over 16 reads, bf16 MFMA.
// COALESCED staging via LDS bounce. Old staging was channel-minor: adjacent
// lanes read 600B apart -> ~12% cache-line efficiency, conv stuck at
// ~2.1 TB/s effective (3x the 50us BW floor). New:
//  (a) copyraw: lane-linear float4 loads of the contiguous 2400-float read
//      (perfect coalescing), fp32->bf16 in flight, uint2 writes to a raw
//      [16][150]us LDS plane (conflict-free).
//  (b) build: slots assembled from raw via ds_read_u16 (<=2-way banks) +
//      one uint4 write per 16B slot (lane-linear, conflict-free).
// LDS image byte-identical to v7 (word 16p+4hh+c = pk(x[4hh+c][p-2],
// x[4hh+c][p-1])); same f2bf numerics. Raw dbuf 2x4800B + slot dbuf
// 2x9856B = 29312B -> 5 blocks/CU; 2-deep pipeline, ONE barrier/iter:
//   copy(r+2) || build(r+1) || MFMA(r) -> barrier
// (copy writes rawB[r&1], build reads rawB[(r+1)&1] = other buffer;
//  build writes xs[(r+1)&1], MFMA reads xs[r&1] = other buffer.)
// ---------------------------------------------------------------------------
__global__ __launch_bounds__(256) void k_conv_sum_mfma(const float* __restrict__ x,
                                                       const float* __restrict__ w,
                                                       float* __restrict__ red) {
  __shared__ unsigned short xs[2][154 * 32];   // slots dbuf, 2 x 9856 B
  __shared__ unsigned short rawB[2][CIN * LL]; // raw bf16 dbuf, 2 x 4800 B
  const int a = blockIdx.x;
  const int tid = threadIdx.x;
  const int lane = tid & 63;
  const int wv = tid >> 6;

  // A-fragments (weights) -> registers. lane holds A[m=lane&15][k=8*(lane>>4)+j]
  short8 afr[2][3];
  {
    const int mrow = lane & 15;
    const int h = lane >> 4;
    for (int mt = 0; mt < 2; ++mt) {
      const int c = mt * 16 + mrow;
      for (int s = 0; s < 3; ++s) {
        short8 f;
#pragma unroll
        for (int j = 0; j < 8; ++j) {
          int ic = 4 * h + (j >> 1);
          int tap = 2 * s + (j & 1);
          float wval = (tap < 5) ? w[c * 80 + ic * 5 + tap] : 0.f;
          f[j] = (short)f2bf(wval);
        }
        afr[mt][s] = f;
      }
    }
  }

  float4v sum[2][3];
#pragma unroll
  for (int mt = 0; mt < 2; ++mt)
#pragma unroll
    for (int nt = 0; nt < 3; ++nt) sum[mt][nt] = (float4v)(0.f);

  const int nbase = wv * 48;
  const int nrow = lane & 15;
  const int hh = lane >> 4;
  const float4v zf = (float4v)(0.f);

  // (a) coalesced copy of read r into rawB[rb] (fp32 -> bf16 in flight)
  auto copyraw = [&](int r, int rb) {
    const float4* xr4 = (const float4*)(x + (size_t)(a * 16 + r) * (CIN * LL));
    unsigned short* raw = rawB[rb];
    for (int i = tid; i < 600; i += 256) {       // 600 float4 = 2400 floats
      float4 u = xr4[i];
      uint2 d;
      d.x = pkbf(u.x, u.y);
      d.y = pkbf(u.z, u.w);
      *(uint2*)&raw[i * 4] = d;                  // 8B write, lane-linear
    }
  };

  // (b) build slots for read r from rawB[rb] into xs[sb]
  auto build = [&](int rb, int sb) {
    const unsigned short* raw = rawB[rb];
    unsigned int* dst = (unsigned int*)xs[sb];
    for (int s = tid; s < 616; s += 256) {
      const int p = s >> 2;
      const int h4 = (s & 3) * 4;                // channel base = 4*hh
      const bool qa = (p >= 2) && (p <= 151);    // px[p]   = x[p-2]
      const bool qb = (p >= 1) && (p <= 150);    // px[p+1] = x[p-1]
      uint4 dw;
      unsigned int v[4];
#pragma unroll
      for (int c = 0; c < 4; ++c) {
        const int base = (h4 + c) * LL;
        unsigned int va = qa ? (unsigned int)raw[base + p - 2] : 0u;
        unsigned int vb = qb ? (unsigned int)raw[base + p - 1] : 0u;
        v[c] = va | (vb << 16);
      }
      dw.x = v[0]; dw.y = v[1]; dw.z = v[2]; dw.w = v[3];
      *(uint4*)&dst[s * 4] = dw;                 // one 16B slot, lane-linear
    }
  };

  // prologue
  copyraw(0, 0);
  __syncthreads();
  copyraw(1, 1);
  build(0, 0);
  __syncthreads();

  for (int r = 0; r < 16; ++r) {
    if (r + 2 < 16) copyraw(r + 2, r & 1);       // rawB[r&1] free (build(r) done)
    if (r + 1 < 16) build((r + 1) & 1, (r + 1) & 1);

    float4v acc[2][3];
#pragma unroll
    for (int s = 0; s < 3; ++s) {
#pragma unroll
      for (int nt = 0; nt < 3; ++nt) {
        int p = nbase + nt * 16 + nrow + 2 * s;
        if (p >= 154) p -= 154;                  // only for discarded cols
        short8 bfrag = *(const short8*)&xs[r & 1][(4 * p + hh) * 8];
#pragma unroll
        for (int mt = 0; mt < 2; ++mt) {
          acc[mt][nt] = __builtin_amdgcn_mfma_f32_16x16x32_bf16(
              afr[mt][s], bfrag, (s == 0) ? zf : acc[mt][nt], 0, 0, 0);
        }
      }
    }
#pragma unroll
    for (int mt = 0; mt < 2; ++mt)
#pragma unroll
      for (int nt = 0; nt < 3; ++nt)
#pragma unroll
        for (int q = 0; q < 4; ++q) sum[mt][nt][q] += fmaxf(acc[mt][nt][q], 0.f);

    __syncthreads();   // build(r+1)/copy(r+2) visible; buffers rotate safely
  }

  // C/D layout (16x16): col = lane&15 -> l, row = (lane>>4)*4+reg -> c
  const int ccol = lane & 15;
  const int crow4 = (lane >> 4) * 4;
  for (int mt = 0; mt < 2; ++mt)
    for (int nt = 0; nt < 3; ++nt) {
      int l = nbase + nt * 16 + ccol;
      if (l < LL) {
#pragma unroll
        for (int q = 0; q < 4; ++q) {
          int c = mt * 16 + crow4 + q;
          red[(size_t)a * (CC * LL) + c * LL + l] = sum[mt][nt][q];
        }
      }
    }
}

// ---------------------------------------------------------------------------
// K2: red2 = relu(comb_w @ [red0|red1]) in place over red0 (unchanged)
// ---------------------------------------------------------------------------
__global__ __launch_bounds__(256) void k_comb(const float* __restrict__ red0,
                                              const float* __restrict__ red1,
                                              const float* __restrict__ cw,
                                              float* __restrict__ out) {
  __shared__ float ins[64][152];
  __shared__ float cwl[64][CC];
  const int a = blockIdx.x;
  const int tid = threadIdx.x;

  for (int i = tid; i < 64 * CC; i += 256) {
    int c = i & 31; int c2 = i >> 5;
    cwl[c2][c] = cw[c * 64 + c2];
  }
  for (int i = tid; i < CC * LL; i += 256) {
    int c2 = i / LL; int l = i - c2 * LL;
    ins[c2][l] = red0[(size_t)a * (CC * LL) + i];
    ins[32 + c2][l] = red1[(size_t)a * (CC * LL) + i];
  }
  __syncthreads();

  const int c = tid & 31;
  const int lg = tid >> 5;
  const int l0 = lg * 19;
  const int nl = (LL - l0 < 19) ? (LL - l0) : 19;
  float v[19];
#pragma unroll
  for (int j = 0; j < 19; ++j) v[j] = 0.f;
  for (int c2 = 0; c2 < 64; ++c2) {
    float wv = cwl[c2][c];
#pragma unroll
    for (int j = 0; j < 19; ++j) v[j] += wv * ins[c2][l0 + j];
  }
  float* o = out + (size_t)a * (CC * LL) + c * LL + l0;
  for (int j = 0; j < nl; ++j) o[j] = fmaxf(v[j], 0.f);
}

// ---------------------------------------------------------------------------
// K4 v10 "k_cattn": fused per-site compressor + cross-attention, all-bf16 LDS
// (unchanged from round 16 — passing).
// ---------------------------------------------------------------------------
#define AKV_US 0
#define BWK    2400
#define BWV    3456
#define BWQ    4512
#define QT_US  4800
#define BPART  3600
#define BMS    4112
#define CF0_US 11136
#define CF1_US 13536
#define KB_US  15936
#define VB_US  20864
#define ARENA  13056
#define FIN0   0
#define FIN1   4928
#define FWS    9856

__device__ __forceinline__ void attn_phase_d(float* __restrict__ ar, int g, int t,
                                             float& ms) {
  unsigned short* aru = (unsigned short*)ar;
  const float scale = 0.17677669529663687f;   // 1/sqrt(32)
  const int rb_us = (g < 6) ? g * 760 : 9024 + (g - 6) * 760;  // ROWPb base
#pragma unroll 1
  for (int cc = 0; cc < 2; ++cc) {
    const int ch = g + 8 * cc;
    if (ch >= 15) break;
    const int r0 = ch * 5;

    float2 acc[5][3];
#pragma unroll
    for (int i = 0; i < 5; ++i)
#pragma unroll
      for (int u = 0; u < 3; ++u) acc[i][u] = make_float2(0.f, 0.f);

#pragma unroll 1
    for (int c2 = 0; c2 < 32; c2 += 2) {
      float2 q01[5];
#pragma unroll
      for (int i = 0; i < 5; ++i) {
        unsigned int qp = *(const unsigned int*)&aru[QT_US + (r0 + i) * 32 + c2];
        q01[i] = make_float2(bflo(qp), bfhi(qp));   // channels c2, c2+1
      }
      const int k0 = KB_US + c2 * 154 + 2 * t;
      const int k1 = k0 + 154;
      unsigned int a0 = *(const unsigned int*)&aru[k0];
      unsigned int a1 = *(const unsigned int*)&aru[k0 + 64];
      unsigned int a2 = *(const unsigned int*)&aru[k0 + 128];
      unsigned int b0 = *(const unsigned int*)&aru[k1];
      unsigned int b1 = *(const unsigned int*)&aru[k1 + 64];
      unsigned int b2 = *(const unsigned int*)&aru[k1 + 128];
      float ka0x = bflo(a0), ka0y = bfhi(a0);
      float ka1x = bflo(a1), ka1y = bfhi(a1);
      float ka2x = bflo(a2), ka2y = bfhi(a2);
      float kb0x = bflo(b0), kb0y = bfhi(b0);
      float kb1x = bflo(b1), kb1y = bfhi(b1);
      float kb2x = bflo(b2), kb2y = bfhi(b2);
#pragma unroll
      for (int i = 0; i < 5; ++i) {
        acc[i][0].x += q01[i].x * ka0x + q01[i].y * kb0x;
        acc[i][0].y += q01[i].x * ka0y + q01[i].y * kb0y;
        acc[i][1].x += q01[i].x * ka1x + q01[i].y * kb1x;
        acc[i][1].y += q01[i].x * ka1y + q01[i].y * kb1y;
        acc[i][2].x += q01[i].x * ka2x + q01[i].y * kb2x;
        acc[i][2].y += q01[i].x * ka2y + q01[i].y * kb2y;
      }
    }

    float inv[5];
#pragma unroll
    for (int i = 0; i < 5; ++i) {
      float s0x = acc[i][0].x * scale, s0y = acc[i][0].y * scale;
      float s1x = acc[i][1].x * scale, s1y = acc[i][1].y * scale;
      float s2x = acc[i][2].x * scale, s2y = acc[i][2].y * scale;
      if (t >= 11) { s2x = -1e30f; s2y = -1e30f; }   // m=128+2t >= 150
      float mx = fmaxf(fmaxf(fmaxf(s0x, s0y), fmaxf(s1x, s1y)), fmaxf(s2x, s2y));
#pragma unroll
      for (int off = 16; off > 0; off >>= 1) mx = fmaxf(mx, __shfl_xor(mx, off, 32));
      float p0x = __expf(s0x - mx), p0y = __expf(s0y - mx);
      float p1x = __expf(s1x - mx), p1y = __expf(s1y - mx);
      float p2x = __expf(s2x - mx), p2y = __expf(s2y - mx);
      float ss = p0x + p0y + p1x + p1y + p2x + p2y;
#pragma unroll
      for (int off = 16; off > 0; off >>= 1) ss += __shfl_xor(ss, off, 32);
      inv[i] = 1.f / ss;
      const int rw = rb_us + i * 152 + 2 * t;
      *(unsigned int*)&aru[rw]      = pkbf(p0x, p0y);
      *(unsigned int*)&aru[rw + 64] = pkbf(p1x, p1y);
      if (t <= 11) *(unsigned int*)&aru[rw + 128] = pkbf(p2x, p2y);  // t=11 -> zeros @150,151
    }

    float pv[5] = {0.f, 0.f, 0.f, 0.f, 0.f};
    const int vb = VB_US + t * 164;
    for (int mq = 0; mq < 38; ++mq) {
      uint2 vv = *(const uint2*)&aru[vb + 4 * mq];
#pragma unroll
      for (int i = 0; i < 5; ++i) {
        uint2 pp = *(const uint2*)&aru[rb_us + i * 152 + 4 * mq];
        pv[i] = bdot2(pp.x, vv.x, pv[i]);
        pv[i] = bdot2(pp.y, vv.y, pv[i]);
      }
    }
#pragma unroll
    for (int i = 0; i < 5; ++i) ms += pv[i] * inv[i];
  }
}

__global__ __launch_bounds__(256) void k_cattn(const float* __restrict__ red,
                                               const float* __restrict__ cw,
                                               const float* __restrict__ wq,
                                               const float* __restrict__ wk,
                                               const float* __restrict__ wv,
                                               const float* __restrict__ wo,
                                               float* __restrict__ cfa,
                                               float* __restrict__ cfs,
                                               float* __restrict__ eout,
                                               int wg) {
  __shared__ float ar[ARENA];
  unsigned short* aru = (unsigned short*)ar;
  const int s = blockIdx.x;
  const int tid = threadIdx.x;
  const int g = tid >> 5;
  const int t = tid & 31;

  float* a0g = cfa + (size_t)(2 * s) * (CC * LC);
  float* a1g = a0g + CC * LC;
  float* sgw = cfs + (size_t)s * (CC * LC);

  // ---- C1: stage comp weights + red pair (stride 154) ----
  for (int i = tid; i < CC * 3 * CC; i += 256) {
    int c = i & 31; int kk = i >> 5;
    ar[FWS + kk * 32 + c] = cw[c * (CC * 3) + kk];
  }
  if (tid < CC) {
    ar[FIN0 + tid * 154 + 0] = 0.f; ar[FIN0 + tid * 154 + 1] = 0.f;
    ar[FIN0 + tid * 154 + 152] = 0.f; ar[FIN0 + tid * 154 + 153] = 0.f;
    ar[FIN1 + tid * 154 + 0] = 0.f; ar[FIN1 + tid * 154 + 1] = 0.f;
    ar[FIN1 + tid * 154 + 152] = 0.f; ar[FIN1 + tid * 154 + 153] = 0.f;
  }
  {
    const float* s0 = red + (size_t)(2 * s) * (CC * LL);
    const float* s1 = s0 + CC * LL;
    for (int i = tid; i < CC * LL; i += 256) {
      int ic = i / LL; int l = i - ic * LL;
      ar[FIN0 + ic * 154 + l + 2] = s0[i];
      ar[FIN1 + ic * 154 + l + 2] = s1[i];
    }
  }
  __syncthreads();

  // ---- C2: compress conv into registers (pre-relu v0, v1) ----
  const int j0 = g * 10;
  const int nj = (LC - j0 < 10) ? (LC - j0) : 10;
  float v0[10], v1[10];
#pragma unroll
  for (int j = 0; j < 10; ++j) { v0[j] = 0.f; v1[j] = 0.f; }
  for (int ic = 0; ic < CC; ++ic) {
    float w0 = ar[FWS + (ic * 3 + 0) * 32 + t];
    float w1 = ar[FWS + (ic * 3 + 1) * 32 + t];
    float w2 = ar[FWS + (ic * 3 + 2) * 32 + t];
    float xa[12], xb[12];
#pragma unroll
    for (int i = 0; i < 12; ++i) {
      // reads beyond index 153 land in the next region; values only feed
      // v[j] with j >= nj which are never stored -> harmless.
      xa[i] = ar[FIN0 + ic * 154 + 2 * j0 + 2 * i];
      xb[i] = ar[FIN1 + ic * 154 + 2 * j0 + 2 * i];
    }
#pragma unroll
    for (int j = 0; j < 10; ++j) {
      v0[j] += w0 * xa[j] + w1 * xa[j + 1] + w2 * xa[j + 2];
      v1[j] += w0 * xb[j] + w1 * xb[j + 1] + w2 * xb[j + 2];
    }
  }
  __syncthreads();   // FIN/FWS reads done -> arena re-laid for attn

  // ---- C3: outputs -> arena (AKVt/CF0t/CF1t bf16) + globals + weights ----
  for (int j = 0; j < nj; ++j) {
    const int jj = j0 + j;
    float r0 = fmaxf(v0[j], 0.f);
    float r1 = fmaxf(v1[j], 0.f);
    float cs = fmaxf(v0[j] + v1[j], 0.f);
    aru[AKV_US + jj * 32 + t]        = f2bf(cs);        // AKVt rows 0..74  = cfs
    aru[AKV_US + (75 + jj) * 32 + t] = f2bf(r0 + r1);   // rows 75..149 = cfa0+cfa1
    aru[CF0_US + jj * 32 + t]        = f2bf(r0);
    aru[CF1_US + jj * 32 + t]        = f2bf(r1);
    if (wg) {                      // only the k_meta stream needs globals
      a0g[t * 75 + jj] = r0;
      a1g[t * 75 + jj] = r1;
      sgw[t * 75 + jj] = cs;
    }
  }
  for (int i = tid; i < CC * CC; i += 256) {
    int o = i >> 5, ii = i & 31;
    ar[BWQ + ii * 33 + o] = wq[i];
    ar[BWK + ii * 33 + o] = wk[i];
    ar[BWV + ii * 33 + o] = wv[i];
  }
  __syncthreads();

  // ---- packs: wq2/wk2/wv2 -> registers (weight LDS dead afterwards) ----
  unsigned int wq2[16], wk2[16], wv2[16];
  {
    float wqc[32], wkc[32], wvc[32];
#pragma unroll
    for (int ii = 0; ii < 32; ++ii) {
      wqc[ii] = ar[BWQ + ii * 33 + t];
      wkc[ii] = ar[BWK + ii * 33 + t];
      wvc[ii] = ar[BWV + ii * 33 + t];
    }
#pragma unroll
    for (int j = 0; j < 16; ++j) {
      wq2[j] = pkbf(wqc[2 * j], wqc[2 * j + 1]);
      wk2[j] = pkbf(wkc[2 * j], wkc[2 * j + 1]);
      wv2[j] = pkbf(wvc[2 * j], wvc[2 * j + 1]);
    }
  }
  __syncthreads();   // all packs done -> QTb may overwrite WK/WV-head

  // ---- B1(0): q0 -> QTb (over dead WK/WV-head), cfsum0 from CF0t ----
  float cfp0 = 0.f;
  for (int row = g; row < 75; row += 8) {
    const unsigned int* cr = (const unsigned int*)&aru[CF0_US + row * 32];
    float acc = 0.f;
#pragma unroll
    for (int j = 0; j < 16; ++j) acc = bdot2(wq2[j], cr[j], acc);
    aru[QT_US + row * 32 + t] = f2bf(acc);
    cfp0 += bflo((unsigned int)aru[CF0_US + row * 32 + t]);
  }
  __syncthreads();   // QTb(0) ready

  // ---- B2 (ONCE): k,v projections via bf16 dot2 -> KBb, VBb ----
  {
    for (int idx = tid; idx < CC * LL; idx += 256) {
      int o = idx & 31, m = idx >> 5;   // o == t (stride-256 keeps low 5 bits)
      const unsigned int* kvrow = (const unsigned int*)&aru[AKV_US + m * 32];
      float ka = 0.f, va = 0.f;
#pragma unroll
      for (int j = 0; j < 16; ++j) {
        unsigned int u = kvrow[j];
        ka = bdot2(wk2[j], u, ka);
        va = bdot2(wv2[j], u, va);
      }
      aru[KB_US + o * 154 + m] = f2bf(ka);
      aru[VB_US + o * 164 + m] = f2bf(va);
    }
    if (tid < 32) *(unsigned int*)&aru[VB_US + tid * 164 + 150] = 0u;  // PV pad
  }
  __syncthreads();   // KBb/VBb ready; AKVt + WQ dead -> ROWPb regions free

  // ---- D(0): allele0 ----
  float ms0 = 0.f;
  attn_phase_d(ar, g, t, ms0);
  __syncthreads();   // D(0) QTb reads done -> B1(1) may rewrite QTb

  // ---- B1(1): q1 -> QTb from CF1t (LDS — no global round-trip) ----
  float cfp1 = 0.f;
  for (int row = g; row < 75; row += 8) {
    const unsigned int* cr = (const unsigned int*)&aru[CF1_US + row * 32];
    float acc = 0.f;
#pragma unroll
    for (int j = 0; j < 16; ++j) acc = bdot2(wq2[j], cr[j], acc);
    aru[QT_US + row * 32 + t] = f2bf(acc);
    cfp1 += bflo((unsigned int)aru[CF1_US + row * 32 + t]);
  }
  __syncthreads();   // QTb(1) ready

  // ---- D(1): allele1 ----
  float ms1 = 0.f;
  attn_phase_d(ar, g, t, ms1);
  __syncthreads();   // D(1) done -> PART region (dead WV tail) safe to write

  ar[BPART + g * 32 + t]       = cfp0 + ms0;
  ar[BPART + 256 + g * 32 + t] = cfp1 + ms1;
  __syncthreads();

  // ---- epilogue: mean over l, project with wo (both alleles) ----
  if (tid < 64) {
    int al = tid >> 5, tt = tid & 31;
    float tot = 0.f;
#pragma unroll
    for (int gg = 0; gg < 8; ++gg) tot += ar[BPART + al * 256 + gg * 32 + tt];
    ar[BMS + al * 32 + tt] = tot * (1.f / 75.f);
  }
  __syncthreads();
  if (tid < 4) {
    int al = tid >> 1, o2 = tid & 1;
    float e = 0.f;
#pragma unroll
    for (int c2 = 0; c2 < CC; ++c2) e += wo[o2 * CC + c2] * ar[BMS + al * 32 + c2];
    eout[s * 4 + tid] = e;   // = eout[(2s+al)*2 + o2]
  }
}

// ---------------------------------------------------------------------------
// K5: meta head per site (unchanged)
// ---------------------------------------------------------------------------
__global__ __launch_bounds__(64) void k_meta(const float* __restrict__ cfs0,
                                             const float* __restrict__ cfa2,
                                             const float* __restrict__ mw,
                                             const float* __restrict__ mb,
                                             float* __restrict__ mout) {
  __shared__ float feat[64];
  __shared__ float lgt[3];
  const int s = blockIdx.x;
  const int tid = threadIdx.x;
  float f = 0.f;
  if (tid < 32) {
    const float* p = cfs0 + (size_t)s * (CC * LC) + tid * LC;
    for (int l = 0; l < LC; ++l) f += p[l];
  } else {
    const float* p0 = cfa2 + (size_t)(2 * s) * (CC * LC) + (tid - 32) * LC;
    const float* p1 = cfa2 + (size_t)(2 * s + 1) * (CC * LC) + (tid - 32) * LC;
    for (int l = 0; l < LC; ++l) f += p0[l] + p1[l];
  }
  feat[tid] = f * (1.f / 75.f);
  __syncthreads();
  if (tid < 3) {
    float acc2 = mb[tid];
    for (int c2 = 0; c2 < 64; ++c2) acc2 += mw[tid * 64 + c2] * feat[c2];
    lgt[tid] = acc2;
  }
  __syncthreads();
  if (tid < 3) {
    float mx = fmaxf(lgt[0], fmaxf(lgt[1], lgt[2]));
    float e0 = __expf(lgt[0] - mx), e1 = __expf(lgt[1] - mx), e2 = __expf(lgt[2] - mx);
    mout[s * 3 + tid] = __expf(lgt[tid] - mx) / (e0 + e1 + e2);
  }
}

// ---------------------------------------------------------------------------
extern "C" void kernel_launch(void* const* d_in, const int* in_sizes, int n_in,
                              void* d_out, int out_size, void* d_ws, size_t ws_size,
                              hipStream_t stream) {
  const float* t0      = (const float*)d_in[0];
  const float* t1      = (const float*)d_in[1];
  const float* conv0_w = (const float*)d_in[2];
  const float* conv1_w = (const float*)d_in[3];
  const float* comp0_w = (const float*)d_in[4];
  const float* comp1_w = (const float*)d_in[5];
  const float* comp2_w = (const float*)d_in[6];
  const float* xq0 = (const float*)d_in[7];
  const float* xk0 = (const float*)d_in[8];
  const float* xv0 = (const float*)d_in[9];
  const float* xo0 = (const float*)d_in[10];
  const float* xq1 = (const float*)d_in[11];
  const float* xk1 = (const float*)d_in[12];
  const float* xv1 = (const float*)d_in[13];
  const float* xo1 = (const float*)d_in[14];
  const float* xq2 = (const float*)d_in[15];
  const float* xk2 = (const float*)d_in[16];
  const float* xv2 = (const float*)d_in[17];
  const float* xo2 = (const float*)d_in[18];
  const float* comb_w = (const float*)d_in[19];
  const float* meta_w = (const float*)d_in[20];
  const float* meta_b = (const float*)d_in[21];

  float* wsf  = (float*)d_ws;
  float* red0 = wsf;
  float* red1 = red0 + (size_t)NA * CC * LL;
  float* cfa  = red1 + (size_t)NA * CC * LL;
  float* cfs0 = cfa + (size_t)NA * CC * LC;
  float* out  = (float*)d_out;

  k_conv_sum_mfma<<<NA, 256, 0, stream>>>(t0, conv0_w, red0);
  k_conv_sum_mfma<<<NA, 256, 0, stream>>>(t1, conv1_w, red1);

  k_cattn<<<NS, 256, 0, stream>>>(red0, comp0_w, xq0, xk0, xv0, xo0,
                                  cfa, cfs0, out + 0, 0);
  k_cattn<<<NS, 256, 0, stream>>>(red1, comp1_w, xq1, xk1, xv1, xo1,
                                  cfa, cfs0, out + 2 * NA, 0);

  k_comb<<<NA, 256, 0, stream>>>(red0, red1, comb_w, red0);
  k_cattn<<<NS, 256, 0, stream>>>(red0, comp2_w, xq2, xk2, xv2, xo2,
                                  cfa, cfs0, out + 4 * NA, 1);

  k_meta<<<NS, 64, 0, stream>>>(cfs0, cfa, meta_w, meta_b, out + 6 * NA);
}